// Round 6
// baseline (170.069 us; speedup 1.0000x reference)
//
#include <hip/hip_runtime.h>

#define BN 200
#define VN 64
#define HIDD 64
#define FINN 32
#define NSW 10
#define EC 63
#define MNE 73
#define NEDGE 146
#define NPACK 512

typedef unsigned short u16;
typedef unsigned int u32;
typedef __attribute__((ext_vector_type(8))) short bf16x8;
typedef __attribute__((ext_vector_type(4))) float f32x4;
typedef __attribute__((ext_vector_type(4))) u32 u32x4;

__device__ __forceinline__ float bfu(u16 u) { return __uint_as_float(((u32)u) << 16); }
__device__ __forceinline__ u16 f2bf(float f) {
    u32 x = __float_as_uint(f);
    u32 r = x + 0x7fffu + ((x >> 16) & 1u);
    return (u16)(r >> 16);
}
__device__ __forceinline__ float cvtv(const void* p, int i, int fl) {
    return fl ? bfu(((const u16*)p)[i]) : ((const float*)p)[i];
}
__device__ __forceinline__ int rfl(int v) { return __builtin_amdgcn_readfirstlane(v); }

// u32-granular XOR swizzle (flips bits 2-4 -> keeps 16B alignment of 4-word blocks)
__device__ __forceinline__ int swzp(int row, int col) { return col ^ ((row & 7) << 2); }

// packed hi/lo bf16 in ONE u32 word: low16 = hi, high16 = lo. 1 DS op per access.
__device__ __forceinline__ float ldp1(const u32* P, int idx) {
    u32 v = P[idx];
    return __uint_as_float(v << 16) + __uint_as_float(v & 0xffff0000u);
}
__device__ __forceinline__ void stp1(u32* P, int idx, float f) {
    u16 h = f2bf(f);
    u16 l = f2bf(f - bfu(h));
    P[idx] = (u32)h | ((u32)l << 16);
}

// load 8-elem MFMA A-fragment (hi & lo planes) from packed u32 LDS, two b128 reads
__device__ __forceinline__ void ldfrag(const u32* P, int i0, int i1, bf16x8* ah, bf16x8* al) {
    u32x4 w0 = *(const u32x4*)&P[i0];
    u32x4 w1 = *(const u32x4*)&P[i1];
    union { bf16x8 v; u32 w[4]; } A, L;
    A.w[0] = (w0.x & 0xffffu) | (w0.y << 16);
    A.w[1] = (w0.z & 0xffffu) | (w0.w << 16);
    A.w[2] = (w1.x & 0xffffu) | (w1.y << 16);
    A.w[3] = (w1.z & 0xffffu) | (w1.w << 16);
    L.w[0] = (w0.x >> 16) | (w0.y & 0xffff0000u);
    L.w[1] = (w0.z >> 16) | (w0.w & 0xffff0000u);
    L.w[2] = (w1.x >> 16) | (w1.y & 0xffff0000u);
    L.w[3] = (w1.z >> 16) | (w1.w & 0xffff0000u);
    *ah = A.v;
    *al = L.v;
}

// ---- DPP wave64 sum-reduce (VALU pipe only, zero DS ops) ----
template <int CTRL>
__device__ __forceinline__ float dppadd(float x) {
    int v = __builtin_amdgcn_update_dpp(0, __float_as_int(x), CTRL, 0xf, 0xf, 1);
    return x + __int_as_float(v);
}
__device__ __forceinline__ float rl63(float x) {
    return __int_as_float(__builtin_amdgcn_readlane(__float_as_int(x), 63));
}

// 4-way LayerNorm+ReLU: 8 interleaved DPP chains (sum & sumsq for 4 rows)
__device__ __forceinline__ void ln4_dpp(float ea, float eb, float ec, float ed,
                                        float& ra, float& rb, float& rc, float& rd) {
    float a1 = ea, b1 = eb, c1 = ec, d1 = ed;
    float a2 = ea * ea, b2 = eb * eb, c2 = ec * ec, d2 = ed * ed;
#define LSTEP(C) a1 = dppadd<C>(a1); b1 = dppadd<C>(b1); c1 = dppadd<C>(c1); d1 = dppadd<C>(d1); \
                 a2 = dppadd<C>(a2); b2 = dppadd<C>(b2); c2 = dppadd<C>(c2); d2 = dppadd<C>(d2);
    LSTEP(0x111) LSTEP(0x112) LSTEP(0x114) LSTEP(0x118) LSTEP(0x142) LSTEP(0x143)
#undef LSTEP
    float s1a = rl63(a1), s2a = rl63(a2);
    float s1b = rl63(b1), s2b = rl63(b2);
    float s1c = rl63(c1), s2c = rl63(c2);
    float s1d = rl63(d1), s2d = rl63(d2);
    float ma = s1a * 0.015625f, mb = s1b * 0.015625f;
    float mc = s1c * 0.015625f, md = s1d * 0.015625f;
    float va = fmaxf(s2a * 0.015625f - ma * ma, 0.f);
    float vb = fmaxf(s2b * 0.015625f - mb * mb, 0.f);
    float vc = fmaxf(s2c * 0.015625f - mc * mc, 0.f);
    float vd = fmaxf(s2d * 0.015625f - md * md, 0.f);
    ra = fmaxf((ea - ma) * rsqrtf(va + 1e-5f), 0.f);
    rb = fmaxf((eb - mb) * rsqrtf(vb + 1e-5f), 0.f);
    rc = fmaxf((ec - mc) * rsqrtf(vc + 1e-5f), 0.f);
    rd = fmaxf((ed - md) * rsqrtf(vd + 1e-5f), 0.f);
}

__device__ __forceinline__ float sigm(float x) {
    return __fdividef(1.f, 1.f + __expf(-x));
}

struct CvtArgs { const void* src[21]; };

// ======== prep: block 0 = topology; blocks 1..NPACK = weight packing ========
__global__ __launch_bounds__(256) void k_prep(CvtArgs ca, const int* __restrict__ eA,
                                              const int* __restrict__ eS,
                                              u16* __restrict__ c1h, u16* __restrict__ c1l,
                                              u16* __restrict__ c2h, u16* __restrict__ c2l,
                                              u16* __restrict__ s1h, u16* __restrict__ s1l,
                                              u16* __restrict__ s2h, u16* __restrict__ s2l,
                                              u16* __restrict__ w0h, u16* __restrict__ w0l,
                                              u16* __restrict__ wlh, u16* __restrict__ wll,
                                              float* __restrict__ ews, float* __restrict__ dinv,
                                              int* __restrict__ row_ptr, int* __restrict__ colp,
                                              int* __restrict__ sw_eidx,
                                              float* __restrict__ dinvD, int* __restrict__ incCnt,
                                              int* __restrict__ incM) {
    int t = threadIdx.x;
    int fl = (((const u16*)ca.src[1])[1] == 0x3F80) ? 1 : 0;
    if (blockIdx.x == 0) {
        __shared__ unsigned char flagL[64 * 65];
        __shared__ float wsL[FINN * 64];
        __shared__ float emL[64];
        __shared__ int degL[64], rpS[65], colS[NEDGE + 16];
        __shared__ int eAL[2 * EC], eSL[2 * NSW];

        if (t < 2 * EC) eAL[t] = eA[t];
        if (t >= 128 && t < 128 + 2 * NSW) eSL[t - 128] = eS[t - 128];
        if (t >= 160 && t < 224) emL[t - 160] = cvtv(ca.src[3], t - 160, fl);
        for (int i = t; i < FINN * 64; i += 256) wsL[i] = cvtv(ca.src[4], i, fl);
        for (int i = t; i < 4096; i += 256) {
            float a = cvtv(ca.src[1], i, fl);
            float s = cvtv(ca.src[2], i, fl);
            int r = i >> 6, c = i & 63;
            flagL[r * 65 + c] = (unsigned char)(((a != 0.f || s != 0.f) ? 1 : 0) |
                                                ((s != 0.f) ? 2 : 0));
        }
        __syncthreads();

        if (t < 128) {
            int j = t >> 6, k = t & 63;
            float a = 0.f;
#pragma unroll
            for (int h = 0; h < FINN; h++) a += emL[j * FINN + h] * wsL[h * 64 + k];
            ews[(j << 6) + k] = a;
        }
        if (t < 64) {
            int d = 0;
#pragma unroll
            for (int w = 0; w < 64; w++) d += flagL[t * 65 + w] & 1;
            degL[t] = d;
            dinv[t] = 1.f / fmaxf((float)d, 1.f);
        }
        __syncthreads();
        if (t == 0) {
            int c = 0;
            for (int v = 0; v < 64; v++) { rpS[v] = c; c += degL[v]; }
            rpS[64] = c;
        }
        __syncthreads();
        if (t < 65) row_ptr[t] = rpS[t];
        if (t < 64) {
            int pos = rpS[t];
#pragma unroll
            for (int w = 0; w < 64; w++) {
                int f = flagL[t * 65 + w];
                if (f & 1) colS[pos++] = w | ((f & 2) ? 256 : 0) | (t << 16);
            }
        }
        __syncthreads();
        int tot = rpS[64];
        if (t < tot) colp[t] = colS[t];
        if (t < NSW) {
            int si = eSL[t], sj = eSL[NSW + t];
            int idx = 0;
            for (int e = rpS[si]; e < rpS[si + 1]; e++)
                if ((colS[e] & 255) == sj) idx = e;
            sw_eidx[t] = idx;
        }
        if (t < 64) {
            dinvD[t] = cvtv(ca.src[18], t * 64 + t, fl);
            int cnt = 0;
            for (int m = 0; m < MNE; m++) {
                int par = (m < EC) ? eAL[m] : eSL[m - EC];
                int chi = (m < EC) ? eAL[EC + m] : eSL[NSW + (m - EC)];
                if (par == t && cnt < 8) incM[t * 8 + cnt++] = (m << 1);
                if (chi == t && cnt < 8) incM[t * 8 + cnt++] = (m << 1) | 1;
            }
            incCnt[t] = cnt;
        }
    } else {
        const int T1 = 36864, T2 = T1 + 3072, T3 = T2 + 65536, T4 = T3 + 4096;
        const int T5 = T4 + 8192, TOT = T5 + 40960;
        for (int i = (blockIdx.x - 1) * 256 + t; i < TOT; i += NPACK * 256) {
            int idx = i;
            const void* src;
            u16 *dh, *dl;
            int K2, N2, nt, rem, loff = 0;
            if (idx < T1) {
                nt = idx / 3072; rem = idx - nt * 3072; src = ca.src[16];
                dh = c1h + idx; dl = c1l + idx; K2 = 192; N2 = 192;
            } else if (idx < T2) {
                idx -= T1; nt = 0; rem = idx; src = ca.src[17];
                dh = c2h + idx; dl = c2l + idx; K2 = 192; N2 = 3;
            } else if (idx < T3) {
                idx -= T2; nt = idx >> 12; rem = idx & 4095; src = ca.src[14];
                dh = s1h + idx; dl = s1l + idx; K2 = 256; N2 = 256;
            } else if (idx < T4) {
                idx -= T3; nt = 0; rem = idx; src = ca.src[15];
                dh = s2h + idx; dl = s2l + idx; K2 = 256; N2 = 4;
            } else if (idx < T5) {
                int j = idx - T4;
                int mt = j >> 11;             // 0=Wi 1=Wj 2=U 3=V  (src 5..8)
                int m2 = j & 2047;
                nt = m2 >> 9; rem = m2 & 511; src = ca.src[5 + mt];
                dh = w0h + j; dl = w0l + j; K2 = 32; N2 = 64;
            } else {
                int j = idx - T5;
                int l = j / 20480;
                int jj = j - l * 20480;
                int mt = jj >> 12;            // 0=Ws 1=Wi 2=Wj 3=U 4=V (src 9..13)
                int m2 = jj & 4095;
                nt = m2 >> 10; rem = m2 & 1023; src = ca.src[9 + mt];
                loff = l * 4096;
                dh = wlh + j; dl = wll + j; K2 = 64; N2 = 64;
            }
            int kb = rem >> 9, r8 = rem & 511, ln = r8 >> 3, jq = r8 & 7;
            int k = kb * 32 + ((ln >> 4) << 3) + jq;
            int n = nt * 16 + (ln & 15);
            float val = 0.f;
            if (n < N2 && k < K2) val = cvtv(src, loff + k * N2 + n, fl);
            u16 h = f2bf(val);
            *dh = h;
            *dl = f2bf(val - bfu(h));
        }
    }
}

#define XI 0
#define XJ 1
#define XU 2
#define XV 3

// ======== fused whole-model kernel ========
__global__ __launch_bounds__(1024) void k_main(
    const void* __restrict__ xraw, const u16* __restrict__ A_u16,
    const int* __restrict__ eA, const int* __restrict__ eS,
    const float* __restrict__ ews, const float* __restrict__ dinv,
    const int* __restrict__ row_ptr, const int* __restrict__ colp,
    const int* __restrict__ sw_eidx,
    const float* __restrict__ dinvD, const int* __restrict__ incCnt, const int* __restrict__ incM,
    const u16* __restrict__ w0h, const u16* __restrict__ w0l,
    const u16* __restrict__ wlh, const u16* __restrict__ wll,
    const u16* __restrict__ c1h, const u16* __restrict__ c1l,
    const u16* __restrict__ c2h, const u16* __restrict__ c2l,
    const u16* __restrict__ s1h, const u16* __restrict__ s1l,
    const u16* __restrict__ s2h, const u16* __restrict__ s2l,
    void* __restrict__ out_v)
{
    __shared__ __align__(16) u32 xP[64 * 64];          // node features, packed hi|lo
    __shared__ __align__(16) u32 sP[NEDGE * 64];       // edge states, packed hi|lo
    __shared__ __align__(16) float preL[NEDGE * 64];   // s@Ws pre-act / gate*xv (f32)
    __shared__ __align__(16) float tLs[4 * 64 * 64];   // xi/xj/xu/xv f32; heads: packed overlay
    __shared__ __align__(16) u32 xgPk[64];
    __shared__ float ewsL[128];
    __shared__ float dinvL[64];
    __shared__ int rpL[65];
    __shared__ int colL[NEDGE + 6];
    __shared__ int swLx[NSW];
    __shared__ int eALs[2 * EC], eSLs[2 * NSW];
    __shared__ float cmoL[EC * 3], smoL[NSW * 4];

    int b = blockIdx.x, t = threadIdx.x;
    int lane = t & 63, wid = t >> 6;          // 16 waves
    int m = lane & 15, quad = lane >> 4;
    int fl = (A_u16[1] == 0x3F80) ? 1 : 0;

    // ---- stage ----
    for (int i = t; i < 2048; i += 1024) {
        int r = i >> 5, c = i & 31;
        stp1(xP, (r << 6) + swzp(r, c), cvtv(xraw, b * 2048 + i, fl));
    }
    if (t < 128) ewsL[t] = ews[t];
    if (t < 64) dinvL[t] = dinv[t];
    if (t < 65) rpL[t] = row_ptr[t];
    if (t < NEDGE) colL[t] = colp[t];
    if (t < NSW) swLx[t] = sw_eidx[t];
    if (t >= 256 && t < 256 + 2 * EC) eALs[t - 256] = eA[t - 256];
    if (t >= 512 && t < 512 + 2 * NSW) eSLs[t - 512] = eS[t - 512];
    __syncthreads();

    // ---- layer 0 transforms: x(64x32) @ {Wi,Wj,U,V}(32x64) ----
    {
        int mat = wid >> 2, Mt = wid & 3;
        const u16* bhp = w0h + mat * 2048;
        const u16* blp = w0l + mat * 2048;
        int row = Mt * 16 + m;
        int c0 = quad * 8;
        bf16x8 ah, al;
        ldfrag(xP, (row << 6) + swzp(row, c0), (row << 6) + swzp(row, c0 + 4), &ah, &al);
        f32x4 acc[4];
#pragma unroll
        for (int nt = 0; nt < 4; nt++) acc[nt] = (f32x4){0.f, 0.f, 0.f, 0.f};
#pragma unroll
        for (int nt = 0; nt < 4; nt++) {
            int o = (nt << 9) + (lane << 3);
            bf16x8 bh = *(const bf16x8*)(bhp + o);
            bf16x8 bl = *(const bf16x8*)(blp + o);
            acc[nt] = __builtin_amdgcn_mfma_f32_16x16x32_bf16(ah, bh, acc[nt], 0, 0, 0);
            acc[nt] = __builtin_amdgcn_mfma_f32_16x16x32_bf16(al, bh, acc[nt], 0, 0, 0);
            acc[nt] = __builtin_amdgcn_mfma_f32_16x16x32_bf16(ah, bl, acc[nt], 0, 0, 0);
        }
#pragma unroll
        for (int nt = 0; nt < 4; nt++)
#pragma unroll
            for (int r = 0; r < 4; r++) {
                int orow = Mt * 16 + quad * 4 + r;
                tLs[mat * 4096 + (orow << 6) + swzp(orow, nt * 16 + m)] = acc[nt][r];
            }
    }
    __syncthreads();

    // ---- layer 0 B1: edge-parallel, 4 edges/iter, 8 interleaved DPP chains ----
    for (int base = 0; base < NEDGE; base += 64) {
        int e0 = base + wid;
        int e1i = e0 + 16, e2i = e0 + 32, e3i = e0 + 48;
        int ok1 = e1i < NEDGE, ok2 = e2i < NEDGE, ok3 = e3i < NEDGE;
        int f1 = ok1 ? e1i : e0, f2 = ok2 ? e2i : e0, f3 = ok3 ? e3i : e0;
        int cp0 = rfl(colL[e0]), cp1 = rfl(colL[f1]);
        int cp2 = rfl(colL[f2]), cp3 = rfl(colL[f3]);
        int w0 = cp0 & 255, v0 = (cp0 >> 16) & 255;
        int w1 = cp1 & 255, v1 = (cp1 >> 16) & 255;
        int w2 = cp2 & 255, v2 = (cp2 >> 16) & 255;
        int w3 = cp3 & 255, v3 = (cp3 >> 16) & 255;
        int si0 = (e0 << 6) + swzp(e0, lane);
        int si1 = (f1 << 6) + swzp(f1, lane);
        int si2 = (f2 << 6) + swzp(f2, lane);
        int si3 = (f3 << 6) + swzp(f3, lane);
        float ee0 = ewsL[(((cp0 >> 8) & 1) << 6) + lane]
                  + tLs[XI * 4096 + (v0 << 6) + swzp(v0, lane)]
                  + tLs[XJ * 4096 + (w0 << 6) + swzp(w0, lane)];
        float ee1 = ewsL[(((cp1 >> 8) & 1) << 6) + lane]
                  + tLs[XI * 4096 + (v1 << 6) + swzp(v1, lane)]
                  + tLs[XJ * 4096 + (w1 << 6) + swzp(w1, lane)];
        float ee2 = ewsL[(((cp2 >> 8) & 1) << 6) + lane]
                  + tLs[XI * 4096 + (v2 << 6) + swzp(v2, lane)]
                  + tLs[XJ * 4096 + (w2 << 6) + swzp(w2, lane)];
        float ee3 = ewsL[(((cp3 >> 8) & 1) << 6) + lane]
                  + tLs[XI * 4096 + (v3 << 6) + swzp(v3, lane)]
                  + tLs[XJ * 4096 + (w3 << 6) + swzp(w3, lane)];
        float h0, h1, h2, h3;
        ln4_dpp(ee0, ee1, ee2, ee3, h0, h1, h2, h3);
        stp1(sP, si0, h0);
        preL[si0] = tLs[XV * 4096 + (w0 << 6) + swzp(w0, lane)] * sigm(h0);
        if (ok1) {
            stp1(sP, si1, h1);
            preL[si1] = tLs[XV * 4096 + (w1 << 6) + swzp(w1, lane)] * sigm(h1);
        }
        if (ok2) {
            stp1(sP, si2, h2);
            preL[si2] = tLs[XV * 4096 + (w2 << 6) + swzp(w2, lane)] * sigm(h2);
        }
        if (ok3) {
            stp1(sP, si3, h3);
            preL[si3] = tLs[XV * 4096 + (w3 << 6) + swzp(w3, lane)] * sigm(h3);
        }
    }
    __syncthreads();

    // ---- layer 0 B2: per-v aggregation (8 interleaved chains) ----
    {
        int v0 = wid << 2;
        int r0 = rfl(rpL[v0]), r1 = rfl(rpL[v0 + 1]), r2 = rfl(rpL[v0 + 2]);
        int r3 = rfl(rpL[v0 + 3]), r4 = rfl(rpL[v0 + 4]);
        float mc0 = 0.f, mc1 = 0.f, mc2 = 0.f, mc3 = 0.f;
        for (int e = r0; e < r1; e++) mc0 += preL[(e << 6) + swzp(e, lane)];
        for (int e = r1; e < r2; e++) mc1 += preL[(e << 6) + swzp(e, lane)];
        for (int e = r2; e < r3; e++) mc2 += preL[(e << 6) + swzp(e, lane)];
        for (int e = r3; e < r4; e++) mc3 += preL[(e << 6) + swzp(e, lane)];
        float z0 = tLs[XU * 4096 + ((v0 + 0) << 6) + swzp(v0 + 0, lane)] + mc0 * dinvL[v0 + 0];
        float z1 = tLs[XU * 4096 + ((v0 + 1) << 6) + swzp(v0 + 1, lane)] + mc1 * dinvL[v0 + 1];
        float z2 = tLs[XU * 4096 + ((v0 + 2) << 6) + swzp(v0 + 2, lane)] + mc2 * dinvL[v0 + 2];
        float z3 = tLs[XU * 4096 + ((v0 + 3) << 6) + swzp(v0 + 3, lane)] + mc3 * dinvL[v0 + 3];
        float h0, h1, h2, h3;
        ln4_dpp(z0, z1, z2, z3, h0, h1, h2, h3);
        stp1(xP, ((v0 + 0) << 6) + swzp(v0 + 0, lane), h0);
        stp1(xP, ((v0 + 1) << 6) + swzp(v0 + 1, lane), h1);
        stp1(xP, ((v0 + 2) << 6) + swzp(v0 + 2, lane), h2);
        stp1(xP, ((v0 + 3) << 6) + swzp(v0 + 3, lane), h3);
    }
    __syncthreads();

    // ---- layers 1,2 ----
    for (int l = 0; l < 2; l++) {
        // (a) x-GEMMs (16 waves) + s-GEMM (40 units over 16 waves)
        {
            int mat = wid >> 2, Mt = wid & 3;
            const u16* bhp = wlh + l * 20480 + (mat + 1) * 4096;
            const u16* blp = wll + l * 20480 + (mat + 1) * 4096;
            int row = Mt * 16 + m;
            f32x4 acc[4];
#pragma unroll
            for (int nt = 0; nt < 4; nt++) acc[nt] = (f32x4){0.f, 0.f, 0.f, 0.f};
#pragma unroll
            for (int kb = 0; kb < 2; kb++) {
                int c0 = kb * 32 + quad * 8;
                bf16x8 ah, al;
                ldfrag(xP, (row << 6) + swzp(row, c0), (row << 6) + swzp(row, c0 + 4), &ah, &al);
#pragma unroll
                for (int nt = 0; nt < 4; nt++) {
                    int o = (((nt << 1) + kb) << 9) + (lane << 3);
                    bf16x8 bh = *(const bf16x8*)(bhp + o);
                    bf16x8 bl = *(const bf16x8*)(blp + o);
                    acc[nt] = __builtin_amdgcn_mfma_f32_16x16x32_bf16(ah, bh, acc[nt], 0, 0, 0);
                    acc[nt] = __builtin_amdgcn_mfma_f32_16x16x32_bf16(al, bh, acc[nt], 0, 0, 0);
                    acc[nt] = __builtin_amdgcn_mfma_f32_16x16x32_bf16(ah, bl, acc[nt], 0, 0, 0);
                }
            }
#pragma unroll
            for (int nt = 0; nt < 4; nt++)
#pragma unroll
                for (int r = 0; r < 4; r++) {
                    int orow = Mt * 16 + quad * 4 + r;
                    tLs[mat * 4096 + (orow << 6) + swzp(orow, nt * 16 + m)] = acc[nt][r];
                }

            const u16* sbh = wlh + l * 20480;   // Ws
            const u16* sbl = wll + l * 20480;
            for (int u = wid; u < 40; u += 16) {
                int rt = u >> 2, ntq = u & 3;
                int srow = rt * 16 + m;
                int ar = (srow > NEDGE - 1) ? (NEDGE - 1) : srow;
                f32x4 sacc = (f32x4){0.f, 0.f, 0.f, 0.f};
#pragma unroll
                for (int kb = 0; kb < 2; kb++) {
                    int c0 = kb * 32 + quad * 8;
                    bf16x8 ah, al;
                    ldfrag(sP, (ar << 6) + swzp(ar, c0), (ar << 6) + swzp(ar, c0 + 4), &ah, &al);
                    int o = (((ntq << 1) + kb) << 9) + (lane << 3);
                    bf16x8 bh = *(const bf16x8*)(sbh + o);
                    bf16x8 bl = *(const bf16x8*)(sbl + o);
                    sacc = __builtin_amdgcn_mfma_f32_16x16x32_bf16(ah, bh, sacc, 0, 0, 0);
                    sacc = __builtin_amdgcn_mfma_f32_16x16x32_bf16(al, bh, sacc, 0, 0, 0);
                    sacc = __builtin_amdgcn_mfma_f32_16x16x32_bf16(ah, bl, sacc, 0, 0, 0);
                }
#pragma unroll
                for (int r = 0; r < 4; r++) {
                    int orow = rt * 16 + quad * 4 + r;
                    if (orow < NEDGE)
                        preL[(orow << 6) + swzp(orow, ntq * 16 + m)] = sacc[r];
                }
            }
        }
        __syncthreads();

        // (b1) edge-parallel update, 4 edges/iter
        for (int base = 0; base < NEDGE; base += 64) {
            int e0 = base + wid;
            int e1i = e0 + 16, e2i = e0 + 32, e3i = e0 + 48;
            int ok1 = e1i < NEDGE, ok2 = e2i < NEDGE, ok3 = e3i < NEDGE;
            int f1 = ok1 ? e1i : e0, f2 = ok2 ? e2i : e0, f3 = ok3 ? e3i : e0;
            int cp0 = rfl(colL[e0]), cp1 = rfl(colL[f1]);
            int cp2 = rfl(colL[f2]), cp3 = rfl(colL[f3]);
            int w0 = cp0 & 255, v0 = (cp0 >> 16) & 255;
            int w1 = cp1 & 255, v1 = (cp1 >> 16) & 255;
            int w2 = cp2 & 255, v2 = (cp2 >> 16) & 255;
            int w3 = cp3 & 255, v3 = (cp3 >> 16) & 255;
            int si0 = (e0 << 6) + swzp(e0, lane);
            int si1 = (f1 << 6) + swzp(f1, lane);
            int si2 = (f2 << 6) + swzp(f2, lane);
            int si3 = (f3 << 6) + swzp(f3, lane);
            float ee0 = preL[si0]
                      + tLs[XI * 4096 + (v0 << 6) + swzp(v0, lane)]
                      + tLs[XJ * 4096 + (w0 << 6) + swzp(w0, lane)];
            float ee1 = preL[si1]
                      + tLs[XI * 4096 + (v1 << 6) + swzp(v1, lane)]
                      + tLs[XJ * 4096 + (w1 << 6) + swzp(w1, lane)];
            float ee2 = preL[si2]
                      + tLs[XI * 4096 + (v2 << 6) + swzp(v2, lane)]
                      + tLs[XJ * 4096 + (w2 << 6) + swzp(w2, lane)];
            float ee3 = preL[si3]
                      + tLs[XI * 4096 + (v3 << 6) + swzp(v3, lane)]
                      + tLs[XJ * 4096 + (w3 << 6) + swzp(w3, lane)];
            float h0, h1, h2, h3;
            ln4_dpp(ee0, ee1, ee2, ee3, h0, h1, h2, h3);
            float s0 = ldp1(sP, si0) + h0;
            stp1(sP, si0, s0);
            preL[si0] = tLs[XV * 4096 + (w0 << 6) + swzp(w0, lane)] * sigm(s0);
            if (ok1) {
                float s1v = ldp1(sP, si1) + h1;
                stp1(sP, si1, s1v);
                preL[si1] = tLs[XV * 4096 + (w1 << 6) + swzp(w1, lane)] * sigm(s1v);
            }
            if (ok2) {
                float s2v = ldp1(sP, si2) + h2;
                stp1(sP, si2, s2v);
                preL[si2] = tLs[XV * 4096 + (w2 << 6) + swzp(w2, lane)] * sigm(s2v);
            }
            if (ok3) {
                float s3v = ldp1(sP, si3) + h3;
                stp1(sP, si3, s3v);
                preL[si3] = tLs[XV * 4096 + (w3 << 6) + swzp(w3, lane)] * sigm(s3v);
            }
        }
        __syncthreads();

        // (b2) per-v aggregation + node update (+ xg partial on last layer)
        {
            int v0 = wid << 2;
            int r0 = rfl(rpL[v0]), r1 = rfl(rpL[v0 + 1]), r2 = rfl(rpL[v0 + 2]);
            int r3 = rfl(rpL[v0 + 3]), r4 = rfl(rpL[v0 + 4]);
            float mc0 = 0.f, mc1 = 0.f, mc2 = 0.f, mc3 = 0.f;
            for (int e = r0; e < r1; e++) mc0 += preL[(e << 6) + swzp(e, lane)];
            for (int e = r1; e < r2; e++) mc1 += preL[(e << 6) + swzp(e, lane)];
            for (int e = r2; e < r3; e++) mc2 += preL[(e << 6) + swzp(e, lane)];
            for (int e = r3; e < r4; e++) mc3 += preL[(e << 6) + swzp(e, lane)];
            float z0 = tLs[XU * 4096 + ((v0 + 0) << 6) + swzp(v0 + 0, lane)] + mc0 * dinvL[v0 + 0];
            float z1 = tLs[XU * 4096 + ((v0 + 1) << 6) + swzp(v0 + 1, lane)] + mc1 * dinvL[v0 + 1];
            float z2 = tLs[XU * 4096 + ((v0 + 2) << 6) + swzp(v0 + 2, lane)] + mc2 * dinvL[v0 + 2];
            float z3 = tLs[XU * 4096 + ((v0 + 3) << 6) + swzp(v0 + 3, lane)] + mc3 * dinvL[v0 + 3];
            float h0, h1, h2, h3;
            ln4_dpp(z0, z1, z2, z3, h0, h1, h2, h3);
            int i0 = ((v0 + 0) << 6) + swzp(v0 + 0, lane);
            int i1 = ((v0 + 1) << 6) + swzp(v0 + 1, lane);
            int i2 = ((v0 + 2) << 6) + swzp(v0 + 2, lane);
            int i3 = ((v0 + 3) << 6) + swzp(v0 + 3, lane);
            float x0 = ldp1(xP, i0) + h0;
            float x1 = ldp1(xP, i1) + h1;
            float x2 = ldp1(xP, i2) + h2;
            float x3 = ldp1(xP, i3) + h3;
            stp1(xP, i0, x0);
            stp1(xP, i1, x1);
            stp1(xP, i2, x2);
            stp1(xP, i3, x3);
            if (l == 1) tLs[(wid << 6) + lane] = x0 + x1 + x2 + x3;   // xg partial
        }
        __syncthreads();
    }

    // ---- xg final ----
    if (t < 64) {
        float s = 0.f;
#pragma unroll
        for (int i = 0; i < 16; i++) s += tLs[(i << 6) + t];
        stp1(xgPk, t, s);
    }
    __syncthreads();

    // ======== heads ========
    u32* hcP = (u32*)tLs;           // 64 x 192 packed
    u32* hsP = (u32*)tLs + 12288;   // 16 x 256 packed

    // ---- H2: cmlp GEMM1 (waves 0-11) ∥ smlp GEMM1 (waves 12-15) ----
    if (wid < 12) {
        int Mt = wid & 3, ntg = wid >> 2;
        int e = Mt * 16 + m; if (e > 62) e = 62;
        int ai = eALs[e], aj = eALs[EC + e];
        f32x4 acc[4];
#pragma unroll
        for (int j = 0; j < 4; j++) acc[j] = (f32x4){0.f, 0.f, 0.f, 0.f};
#pragma unroll
        for (int kb = 0; kb < 6; kb++) {
            int k = kb * 32 + quad * 8;
            bf16x8 ah, al;
            if (k < 64) {
                ldfrag(xP, (ai << 6) + swzp(ai, k), (ai << 6) + swzp(ai, k + 4), &ah, &al);
            } else if (k < 128) {
                int c = k - 64;
                ldfrag(xP, (aj << 6) + swzp(aj, c), (aj << 6) + swzp(aj, c + 4), &ah, &al);
            } else {
                int c = k - 128;
                ldfrag(xgPk, c, c + 4, &ah, &al);
            }
#pragma unroll
            for (int j = 0; j < 4; j++) {
                int nt = ntg * 4 + j;
                int o = ((nt * 6 + kb) << 9) + (lane << 3);
                bf16x8 bh = *(const bf16x8*)(c1h + o);
                bf16x8 bl = *(const bf16x8*)(c1l + o);
                acc[j] = __builtin_amdgcn_mfma_f32_16x16x32_bf16(ah, bh, acc[j], 0, 0, 0);
                acc[j] = __builtin_amdgcn_mfma_f32_16x16x32_bf16(al, bh, acc[j], 0, 0, 0);
                acc[j] = __builtin_amdgcn_mfma_f32_16x16x32_bf16(ah, bl, acc[j], 0, 0, 0);
            }
        }
#pragma unroll
        for (int j = 0; j < 4; j++) {
            int nt = ntg * 4 + j;
#pragma unroll
            for (int r = 0; r < 4; r++) {
                int row = Mt * 16 + quad * 4 + r;
                stp1(hcP, row * 192 + swzp(row, nt * 16 + m), fmaxf(acc[j][r], 0.f));
            }
        }
    } else {
        int e2 = (m > 9) ? 9 : m;
        int si = eSLs[e2], sj = eSLs[NSW + e2];
        int sw = swLx[e2];
        f32x4 accS[4];
#pragma unroll
        for (int j = 0; j < 4; j++) accS[j] = (f32x4){0.f, 0.f, 0.f, 0.f};
#pragma unroll
        for (int kb = 0; kb < 8; kb++) {
            int k = kb * 32 + quad * 8;
            bf16x8 ah, al;
            if (k < 64) {
                ldfrag(sP, (sw << 6) + swzp(sw, k), (sw << 6) + swzp(sw, k + 4), &ah, &al);
            } else if (k < 128) {
                int c = k - 64;
                ldfrag(xP, (si << 6) + swzp(si, c), (si << 6) + swzp(si, c + 4), &ah, &al);
            } else if (k < 192) {
                int c = k - 128;
                ldfrag(xP, (sj << 6) + swzp(sj, c), (sj << 6) + swzp(sj, c + 4), &ah, &al);
            } else {
                int c = k - 192;
                ldfrag(xgPk, c, c + 4, &ah, &al);
            }
#pragma unroll
            for (int j = 0; j < 4; j++) {
                int nt = (wid - 12) * 4 + j;
                int o = ((nt * 8 + kb) << 9) + (lane << 3);
                bf16x8 bh = *(const bf16x8*)(s1h + o);
                bf16x8 bl = *(const bf16x8*)(s1l + o);
                accS[j] = __builtin_amdgcn_mfma_f32_16x16x32_bf16(ah, bh, accS[j], 0, 0, 0);
                accS[j] = __builtin_amdgcn_mfma_f32_16x16x32_bf16(al, bh, accS[j], 0, 0, 0);
                accS[j] = __builtin_amdgcn_mfma_f32_16x16x32_bf16(ah, bl, accS[j], 0, 0, 0);
            }
        }
#pragma unroll
        for (int j = 0; j < 4; j++) {
            int nt = (wid - 12) * 4 + j;
#pragma unroll
            for (int r = 0; r < 4; r++) {
                int row = quad * 4 + r;
                stp1(hsP, (row << 8) + swzp(row, nt * 16 + m), fmaxf(accS[j][r], 0.f));
            }
        }
    }
    __syncthreads();

    // ---- H3: cmlp GEMM2 (waves 0-3) ∥ smlp GEMM2 (wave 4) ----
    if (wid < 4) {
        f32x4 accD = (f32x4){0.f, 0.f, 0.f, 0.f};
        int row = wid * 16 + m;
#pragma unroll
        for (int kb = 0; kb < 6; kb++) {
            int c0 = kb * 32 + quad * 8;
            bf16x8 ah, al;
            ldfrag(hcP, row * 192 + swzp(row, c0), row * 192 + swzp(row, c0 + 4), &ah, &al);
            int o = (kb << 9) + (lane << 3);
            bf16x8 bh = *(const bf16x8*)(c2h + o);
            bf16x8 bl = *(const bf16x8*)(c2l + o);
            accD = __builtin_amdgcn_mfma_f32_16x16x32_bf16(ah, bh, accD, 0, 0, 0);
            accD = __builtin_amdgcn_mfma_f32_16x16x32_bf16(al, bh, accD, 0, 0, 0);
            accD = __builtin_amdgcn_mfma_f32_16x16x32_bf16(ah, bl, accD, 0, 0, 0);
        }
#pragma unroll
        for (int r = 0; r < 4; r++) {
            int row2 = wid * 16 + quad * 4 + r;
            if (row2 < EC && m < 3)
                cmoL[row2 * 3 + m] = 1.f / (1.f + __expf(-accD[r]));
        }
    } else if (wid == 4) {
        f32x4 accT = (f32x4){0.f, 0.f, 0.f, 0.f};
#pragma unroll
        for (int kb = 0; kb < 8; kb++) {
            int c0 = kb * 32 + quad * 8;
            bf16x8 ah, al;
            ldfrag(hsP, (m << 8) + swzp(m, c0), (m << 8) + swzp(m, c0 + 4), &ah, &al);
            int o = (kb << 9) + (lane << 3);
            bf16x8 bh = *(const bf16x8*)(s2h + o);
            bf16x8 bl = *(const bf16x8*)(s2l + o);
            accT = __builtin_amdgcn_mfma_f32_16x16x32_bf16(ah, bh, accT, 0, 0, 0);
            accT = __builtin_amdgcn_mfma_f32_16x16x32_bf16(al, bh, accT, 0, 0, 0);
            accT = __builtin_amdgcn_mfma_f32_16x16x32_bf16(ah, bl, accT, 0, 0, 0);
        }
#pragma unroll
        for (int r = 0; r < 4; r++) {
            int row = quad * 4 + r;
            if (row < NSW && m < 4)
                smoL[row * 4 + m] = 1.f / (1.f + __expf(-accT[r]));
        }
    }
    __syncthreads();

    // ---- final assembly ----
    if (t < 2 * MNE + VN) {
        float val;
        if (t < MNE) {
            val = (t < EC) ? cmoL[t * 3] - 0.5f : smoL[(t - EC) * 4 + 1] - 0.5f;
        } else if (t < MNE + VN) {
            int i = t - MNE;
            if (i == 0) {
                val = 1.0f;
            } else {
                float acc = 0.f;
                int c = incCnt[i];
                for (int q = 0; q < c; q++) {
                    int em = incM[i * 8 + q];
                    int mm = em >> 1, role = em & 1;
                    float vv = (mm < EC) ? 0.9f + 0.2f * cmoL[mm * 3 + 1 + role]
                                         : 0.9f + 0.2f * smoL[(mm - EC) * 4 + 2 + role];
                    acc += vv;
                }
                val = acc * dinvD[i];
            }
        } else {
            int mm = t - (MNE + VN);
            val = (mm < EC) ? 1.0f : smoL[(mm - EC) * 4];
        }
        size_t oidx = (size_t)b * (2 * MNE + VN) + t;
        if (fl) ((u16*)out_v)[oidx] = f2bf(val);
        else    ((float*)out_v)[oidx] = val;
    }
}

extern "C" void kernel_launch(void* const* d_in, const int* in_sizes, int n_in,
                              void* d_out, int out_size, void* d_ws, size_t ws_size,
                              hipStream_t stream) {
    const int* eA = (const int*)d_in[21];
    const int* eS = (const int*)d_in[22];

    float* pool = (float*)d_ws;
    float* ews     = pool;                       // 128
    float* dinv    = ews + 128;                  // 64
    float* dinvD   = dinv + 64;                  // 64
    int*   row_ptr = (int*)(dinvD + 64);         // 80
    int*   colp    = row_ptr + 80;               // 256
    int*   sw_eidx = colp + 256;                 // 16
    int*   incCnt  = sw_eidx + 16;               // 64
    int*   incM    = incCnt + 64;                // 512
    u16*   c1h = (u16*)(incM + 512);
    u16*   c1l = c1h + 36864;
    u16*   c2h = c1l + 36864;
    u16*   c2l = c2h + 3072;
    u16*   s1h = c2l + 3072;
    u16*   s1l = s1h + 65536;
    u16*   s2h = s1l + 65536;
    u16*   s2l = s2h + 4096;
    u16*   w0h = s2l + 4096;
    u16*   w0l = w0h + 8192;
    u16*   wlh = w0l + 8192;
    u16*   wll = wlh + 40960;

    CvtArgs ca;
    for (int i = 0; i < 21; i++) ca.src[i] = d_in[i];

    k_prep<<<1 + NPACK, 256, 0, stream>>>(ca, eA, eS,
                                          c1h, c1l, c2h, c2l, s1h, s1l, s2h, s2l,
                                          w0h, w0l, wlh, wll,
                                          ews, dinv, row_ptr, colp, sw_eidx,
                                          dinvD, incCnt, incM);

    k_main<<<BN, 1024, 0, stream>>>(d_in[0], (const u16*)d_in[1], eA, eS,
                                    ews, dinv, row_ptr, colp, sw_eidx,
                                    dinvD, incCnt, incM,
                                    w0h, w0l, wlh, wll,
                                    c1h, c1l, c2h, c2l, s1h, s1l, s2h, s2l,
                                    d_out);
}

// Round 7
// 152.702 us; speedup vs baseline: 1.1137x; 1.1137x over previous
//
#include <hip/hip_runtime.h>

#define BN 200
#define VN 64
#define HIDD 64
#define FINN 32
#define NSW 10
#define EC 63
#define MNE 73
#define NEDGE 146
#define NPACK 256

typedef unsigned short u16;
typedef unsigned int u32;
typedef _Float16 f16;
typedef __attribute__((ext_vector_type(8))) _Float16 f16x8;
typedef __attribute__((ext_vector_type(4))) float f32x4;

__device__ __forceinline__ float bfu(u16 u) { return __uint_as_float(((u32)u) << 16); }
__device__ __forceinline__ u16 f2bf(float f) {
    u32 x = __float_as_uint(f);
    u32 r = x + 0x7fffu + ((x >> 16) & 1u);
    return (u16)(r >> 16);
}
__device__ __forceinline__ float cvtv(const void* p, int i, int fl) {
    return fl ? bfu(((const u16*)p)[i]) : ((const float*)p)[i];
}
__device__ __forceinline__ int rfl(int v) { return __builtin_amdgcn_readfirstlane(v); }

// swizzles: u32-granular (f32 planes) and u16-granular (f16 planes); both keep 16B groups
__device__ __forceinline__ int swzp(int row, int col) { return col ^ ((row & 7) << 2); }
__device__ __forceinline__ int swz16(int row, int col) { return col ^ ((row & 7) << 3); }

// f16 state: 1 DS op + 1 cvt per access
__device__ __forceinline__ float ldh(const u16* P, int i) {
    union { u16 u; f16 h; } c; c.u = P[i];
    return (float)c.h;
}
__device__ __forceinline__ void sth(u16* P, int i, float f) {
    union { u16 u; f16 h; } c; c.h = (f16)f;
    P[i] = c.u;
}
__device__ __forceinline__ u16 f2h(float f) {
    union { u16 u; f16 h; } c; c.h = (f16)f;
    return c.u;
}
// 8-elem MFMA A-fragment: ONE ds_read_b128, no unpack
__device__ __forceinline__ f16x8 ldfragh(const u16* P, int i0) {
    return *(const f16x8*)&P[i0];
}

// ---- DPP wave64 sum-reduce (VALU pipe only) ----
template <int CTRL>
__device__ __forceinline__ float dppadd(float x) {
    int v = __builtin_amdgcn_update_dpp(0, __float_as_int(x), CTRL, 0xf, 0xf, 1);
    return x + __int_as_float(v);
}
__device__ __forceinline__ float rl63(float x) {
    return __int_as_float(__builtin_amdgcn_readlane(__float_as_int(x), 63));
}

// 4-way LayerNorm+ReLU: 8 interleaved DPP chains
__device__ __forceinline__ void ln4_dpp(float ea, float eb, float ec, float ed,
                                        float& ra, float& rb, float& rc, float& rd) {
    float a1 = ea, b1 = eb, c1 = ec, d1 = ed;
    float a2 = ea * ea, b2 = eb * eb, c2 = ec * ec, d2 = ed * ed;
#define LSTEP(C) a1 = dppadd<C>(a1); b1 = dppadd<C>(b1); c1 = dppadd<C>(c1); d1 = dppadd<C>(d1); \
                 a2 = dppadd<C>(a2); b2 = dppadd<C>(b2); c2 = dppadd<C>(c2); d2 = dppadd<C>(d2);
    LSTEP(0x111) LSTEP(0x112) LSTEP(0x114) LSTEP(0x118) LSTEP(0x142) LSTEP(0x143)
#undef LSTEP
    float s1a = rl63(a1), s2a = rl63(a2);
    float s1b = rl63(b1), s2b = rl63(b2);
    float s1c = rl63(c1), s2c = rl63(c2);
    float s1d = rl63(d1), s2d = rl63(d2);
    float ma = s1a * 0.015625f, mb = s1b * 0.015625f;
    float mc = s1c * 0.015625f, md = s1d * 0.015625f;
    float va = fmaxf(s2a * 0.015625f - ma * ma, 0.f);
    float vb = fmaxf(s2b * 0.015625f - mb * mb, 0.f);
    float vc = fmaxf(s2c * 0.015625f - mc * mc, 0.f);
    float vd = fmaxf(s2d * 0.015625f - md * md, 0.f);
    ra = fmaxf((ea - ma) * rsqrtf(va + 1e-5f), 0.f);
    rb = fmaxf((eb - mb) * rsqrtf(vb + 1e-5f), 0.f);
    rc = fmaxf((ec - mc) * rsqrtf(vc + 1e-5f), 0.f);
    rd = fmaxf((ed - md) * rsqrtf(vd + 1e-5f), 0.f);
}

__device__ __forceinline__ float sigm(float x) {
    return __fdividef(1.f, 1.f + __expf(-x));
}

struct CvtArgs { const void* src[21]; };

// ======== prep: block 0 = topology; blocks 1..NPACK = single-plane f16 weight packing ========
__global__ __launch_bounds__(256) void k_prep(CvtArgs ca, const int* __restrict__ eA,
                                              const int* __restrict__ eS,
                                              u16* __restrict__ c1p, u16* __restrict__ c2p,
                                              u16* __restrict__ s1p, u16* __restrict__ s2p,
                                              u16* __restrict__ w0p, u16* __restrict__ wlp,
                                              float* __restrict__ ews, float* __restrict__ dinv,
                                              int* __restrict__ row_ptr, int* __restrict__ colp,
                                              int* __restrict__ sw_eidx,
                                              float* __restrict__ dinvD, int* __restrict__ incCnt,
                                              int* __restrict__ incM) {
    int t = threadIdx.x;
    int fl = (((const u16*)ca.src[1])[1] == 0x3F80) ? 1 : 0;
    if (blockIdx.x == 0) {
        __shared__ unsigned char flagL[64 * 65];
        __shared__ float wsL[FINN * 64];
        __shared__ float emL[64];
        __shared__ int degL[64], rpS[65], colS[NEDGE + 16];
        __shared__ int eAL[2 * EC], eSL[2 * NSW];

        if (t < 2 * EC) eAL[t] = eA[t];
        if (t >= 128 && t < 128 + 2 * NSW) eSL[t - 128] = eS[t - 128];
        if (t >= 160 && t < 224) emL[t - 160] = cvtv(ca.src[3], t - 160, fl);
        for (int i = t; i < FINN * 64; i += 256) wsL[i] = cvtv(ca.src[4], i, fl);
        for (int i = t; i < 4096; i += 256) {
            float a = cvtv(ca.src[1], i, fl);
            float s = cvtv(ca.src[2], i, fl);
            int r = i >> 6, c = i & 63;
            flagL[r * 65 + c] = (unsigned char)(((a != 0.f || s != 0.f) ? 1 : 0) |
                                                ((s != 0.f) ? 2 : 0));
        }
        __syncthreads();

        if (t < 128) {
            int j = t >> 6, k = t & 63;
            float a = 0.f;
#pragma unroll
            for (int h = 0; h < FINN; h++) a += emL[j * FINN + h] * wsL[h * 64 + k];
            ews[(j << 6) + k] = a;
        }
        if (t < 64) {
            int d = 0;
#pragma unroll
            for (int w = 0; w < 64; w++) d += flagL[t * 65 + w] & 1;
            degL[t] = d;
            dinv[t] = 1.f / fmaxf((float)d, 1.f);
        }
        __syncthreads();
        if (t == 0) {
            int c = 0;
            for (int v = 0; v < 64; v++) { rpS[v] = c; c += degL[v]; }
            rpS[64] = c;
        }
        __syncthreads();
        if (t < 65) row_ptr[t] = rpS[t];
        if (t < 64) {
            int pos = rpS[t];
#pragma unroll
            for (int w = 0; w < 64; w++) {
                int f = flagL[t * 65 + w];
                if (f & 1) colS[pos++] = w | ((f & 2) ? 256 : 0) | (t << 16);
            }
        }
        __syncthreads();
        int tot = rpS[64];
        if (t < tot) colp[t] = colS[t];
        if (t < NSW) {
            int si = eSL[t], sj = eSL[NSW + t];
            int idx = 0;
            for (int e = rpS[si]; e < rpS[si + 1]; e++)
                if ((colS[e] & 255) == sj) idx = e;
            sw_eidx[t] = idx;
        }
        if (t < 64) {
            dinvD[t] = cvtv(ca.src[18], t * 64 + t, fl);
            int cnt = 0;
            for (int m = 0; m < MNE; m++) {
                int par = (m < EC) ? eAL[m] : eSL[m - EC];
                int chi = (m < EC) ? eAL[EC + m] : eSL[NSW + (m - EC)];
                if (par == t && cnt < 8) incM[t * 8 + cnt++] = (m << 1);
                if (chi == t && cnt < 8) incM[t * 8 + cnt++] = (m << 1) | 1;
            }
            incCnt[t] = cnt;
        }
    } else {
        const int T1 = 36864, T2 = T1 + 3072, T3 = T2 + 65536, T4 = T3 + 4096;
        const int T5 = T4 + 8192, TOT = T5 + 40960;
        for (int i = (blockIdx.x - 1) * 256 + t; i < TOT; i += NPACK * 256) {
            int idx = i;
            const void* src;
            u16* dp;
            int K2, N2, nt, rem, loff = 0;
            if (idx < T1) {
                nt = idx / 3072; rem = idx - nt * 3072; src = ca.src[16];
                dp = c1p + idx; K2 = 192; N2 = 192;
            } else if (idx < T2) {
                idx -= T1; nt = 0; rem = idx; src = ca.src[17];
                dp = c2p + idx; K2 = 192; N2 = 3;
            } else if (idx < T3) {
                idx -= T2; nt = idx >> 12; rem = idx & 4095; src = ca.src[14];
                dp = s1p + idx; K2 = 256; N2 = 256;
            } else if (idx < T4) {
                idx -= T3; nt = 0; rem = idx; src = ca.src[15];
                dp = s2p + idx; K2 = 256; N2 = 4;
            } else if (idx < T5) {
                int j = idx - T4;
                int mt = j >> 11;             // 0=Wi 1=Wj 2=U 3=V  (src 5..8)
                int m2 = j & 2047;
                nt = m2 >> 9; rem = m2 & 511; src = ca.src[5 + mt];
                dp = w0p + j; K2 = 32; N2 = 64;
            } else {
                int j = idx - T5;
                int l = j / 20480;
                int jj = j - l * 20480;
                int mt = jj >> 12;            // 0=Ws 1=Wi 2=Wj 3=U 4=V (src 9..13)
                int m2 = jj & 4095;
                nt = m2 >> 10; rem = m2 & 1023; src = ca.src[9 + mt];
                loff = l * 4096;
                dp = wlp + j; K2 = 64; N2 = 64;
            }
            int kb = rem >> 9, r8 = rem & 511, ln = r8 >> 3, jq = r8 & 7;
            int k = kb * 32 + ((ln >> 4) << 3) + jq;
            int n = nt * 16 + (ln & 15);
            float val = 0.f;
            if (n < N2 && k < K2) val = cvtv(src, loff + k * N2 + n, fl);
            *dp = f2h(val);
        }
    }
}

#define XI 0
#define XJ 1
#define XU 2
#define XV 3

// ======== fused whole-model kernel (single-f16 datapath) ========
__global__ __launch_bounds__(1024) void k_main(
    const void* __restrict__ xraw, const u16* __restrict__ A_u16,
    const int* __restrict__ eA, const int* __restrict__ eS,
    const float* __restrict__ ews, const float* __restrict__ dinv,
    const int* __restrict__ row_ptr, const int* __restrict__ colp,
    const int* __restrict__ sw_eidx,
    const float* __restrict__ dinvD, const int* __restrict__ incCnt, const int* __restrict__ incM,
    const u16* __restrict__ w0p, const u16* __restrict__ wlp,
    const u16* __restrict__ c1p, const u16* __restrict__ c2p,
    const u16* __restrict__ s1p, const u16* __restrict__ s2p,
    void* __restrict__ out_v)
{
    __shared__ __align__(16) u16 xPh[64 * 64];         // node features, f16 (8 KB)
    __shared__ __align__(16) u16 sPh[NEDGE * 64];      // edge states, f16 (18.7 KB)
    __shared__ __align__(16) float preL[NEDGE * 64];   // s@Ws pre-act / gate*xv (f32)
    __shared__ __align__(16) float tLs[4 * 64 * 64];   // xi/xj/xu/xv f32; heads: f16 overlay
    __shared__ __align__(16) u16 xg16[64];
    __shared__ float ewsL[128];
    __shared__ float dinvL[64];
    __shared__ int rpL[65];
    __shared__ int colL[NEDGE + 6];
    __shared__ int swLx[NSW];
    __shared__ int eALs[2 * EC], eSLs[2 * NSW];
    __shared__ float cmoL[EC * 3], smoL[NSW * 4];

    int b = blockIdx.x, t = threadIdx.x;
    int lane = t & 63, wid = t >> 6;          // 16 waves
    int m = lane & 15, quad = lane >> 4;
    int fl = (A_u16[1] == 0x3F80) ? 1 : 0;

    // ---- stage ----
    for (int i = t; i < 2048; i += 1024) {
        int r = i >> 5, c = i & 31;
        sth(xPh, (r << 6) + swz16(r, c), cvtv(xraw, b * 2048 + i, fl));
    }
    if (t < 128) ewsL[t] = ews[t];
    if (t < 64) dinvL[t] = dinv[t];
    if (t < 65) rpL[t] = row_ptr[t];
    if (t < NEDGE) colL[t] = colp[t];
    if (t < NSW) swLx[t] = sw_eidx[t];
    if (t >= 256 && t < 256 + 2 * EC) eALs[t - 256] = eA[t - 256];
    if (t >= 512 && t < 512 + 2 * NSW) eSLs[t - 512] = eS[t - 512];
    __syncthreads();

    // ---- layer 0 transforms: x(64x32) @ {Wi,Wj,U,V}(32x64), 1 MFMA per tile ----
    {
        int mat = wid >> 2, Mt = wid & 3;
        const u16* bp = w0p + mat * 2048;
        int row = Mt * 16 + m;
        f16x8 a = ldfragh(xPh, (row << 6) + swz16(row, quad * 8));
        f32x4 acc[4];
#pragma unroll
        for (int nt = 0; nt < 4; nt++) {
            f16x8 bfr = ldfragh(bp, (nt << 9) + (lane << 3));
            acc[nt] = __builtin_amdgcn_mfma_f32_16x16x32_f16(a, bfr, (f32x4){0.f, 0.f, 0.f, 0.f}, 0, 0, 0);
        }
#pragma unroll
        for (int nt = 0; nt < 4; nt++)
#pragma unroll
            for (int r = 0; r < 4; r++) {
                int orow = Mt * 16 + quad * 4 + r;
                tLs[mat * 4096 + (orow << 6) + swzp(orow, nt * 16 + m)] = acc[nt][r];
            }
    }
    __syncthreads();

    // ---- layer 0 B1: edge-parallel, 4 edges/iter ----
    for (int base = 0; base < NEDGE; base += 64) {
        int e0 = base + wid;
        int e1i = e0 + 16, e2i = e0 + 32, e3i = e0 + 48;
        int ok1 = e1i < NEDGE, ok2 = e2i < NEDGE, ok3 = e3i < NEDGE;
        int f1 = ok1 ? e1i : e0, f2 = ok2 ? e2i : e0, f3 = ok3 ? e3i : e0;
        int cp0 = rfl(colL[e0]), cp1 = rfl(colL[f1]);
        int cp2 = rfl(colL[f2]), cp3 = rfl(colL[f3]);
        int w0 = cp0 & 255, v0 = (cp0 >> 16) & 255;
        int w1 = cp1 & 255, v1 = (cp1 >> 16) & 255;
        int w2 = cp2 & 255, v2 = (cp2 >> 16) & 255;
        int w3 = cp3 & 255, v3 = (cp3 >> 16) & 255;
        int h0i = (e0 << 6) + swz16(e0, lane);
        int h1i = (f1 << 6) + swz16(f1, lane);
        int h2i = (f2 << 6) + swz16(f2, lane);
        int h3i = (f3 << 6) + swz16(f3, lane);
        int p0i = (e0 << 6) + swzp(e0, lane);
        int p1i = (f1 << 6) + swzp(f1, lane);
        int p2i = (f2 << 6) + swzp(f2, lane);
        int p3i = (f3 << 6) + swzp(f3, lane);
        float ee0 = ewsL[(((cp0 >> 8) & 1) << 6) + lane]
                  + tLs[XI * 4096 + (v0 << 6) + swzp(v0, lane)]
                  + tLs[XJ * 4096 + (w0 << 6) + swzp(w0, lane)];
        float ee1 = ewsL[(((cp1 >> 8) & 1) << 6) + lane]
                  + tLs[XI * 4096 + (v1 << 6) + swzp(v1, lane)]
                  + tLs[XJ * 4096 + (w1 << 6) + swzp(w1, lane)];
        float ee2 = ewsL[(((cp2 >> 8) & 1) << 6) + lane]
                  + tLs[XI * 4096 + (v2 << 6) + swzp(v2, lane)]
                  + tLs[XJ * 4096 + (w2 << 6) + swzp(w2, lane)];
        float ee3 = ewsL[(((cp3 >> 8) & 1) << 6) + lane]
                  + tLs[XI * 4096 + (v3 << 6) + swzp(v3, lane)]
                  + tLs[XJ * 4096 + (w3 << 6) + swzp(w3, lane)];
        float h0, h1, h2, h3;
        ln4_dpp(ee0, ee1, ee2, ee3, h0, h1, h2, h3);
        sth(sPh, h0i, h0);
        preL[p0i] = tLs[XV * 4096 + (w0 << 6) + swzp(w0, lane)] * sigm(h0);
        if (ok1) {
            sth(sPh, h1i, h1);
            preL[p1i] = tLs[XV * 4096 + (w1 << 6) + swzp(w1, lane)] * sigm(h1);
        }
        if (ok2) {
            sth(sPh, h2i, h2);
            preL[p2i] = tLs[XV * 4096 + (w2 << 6) + swzp(w2, lane)] * sigm(h2);
        }
        if (ok3) {
            sth(sPh, h3i, h3);
            preL[p3i] = tLs[XV * 4096 + (w3 << 6) + swzp(w3, lane)] * sigm(h3);
        }
    }
    __syncthreads();

    // ---- layer 0 B2: per-v aggregation ----
    {
        int v0 = wid << 2;
        int r0 = rfl(rpL[v0]), r1 = rfl(rpL[v0 + 1]), r2 = rfl(rpL[v0 + 2]);
        int r3 = rfl(rpL[v0 + 3]), r4 = rfl(rpL[v0 + 4]);
        float mc0 = 0.f, mc1 = 0.f, mc2 = 0.f, mc3 = 0.f;
        for (int e = r0; e < r1; e++) mc0 += preL[(e << 6) + swzp(e, lane)];
        for (int e = r1; e < r2; e++) mc1 += preL[(e << 6) + swzp(e, lane)];
        for (int e = r2; e < r3; e++) mc2 += preL[(e << 6) + swzp(e, lane)];
        for (int e = r3; e < r4; e++) mc3 += preL[(e << 6) + swzp(e, lane)];
        float z0 = tLs[XU * 4096 + ((v0 + 0) << 6) + swzp(v0 + 0, lane)] + mc0 * dinvL[v0 + 0];
        float z1 = tLs[XU * 4096 + ((v0 + 1) << 6) + swzp(v0 + 1, lane)] + mc1 * dinvL[v0 + 1];
        float z2 = tLs[XU * 4096 + ((v0 + 2) << 6) + swzp(v0 + 2, lane)] + mc2 * dinvL[v0 + 2];
        float z3 = tLs[XU * 4096 + ((v0 + 3) << 6) + swzp(v0 + 3, lane)] + mc3 * dinvL[v0 + 3];
        float h0, h1, h2, h3;
        ln4_dpp(z0, z1, z2, z3, h0, h1, h2, h3);
        sth(xPh, ((v0 + 0) << 6) + swz16(v0 + 0, lane), h0);
        sth(xPh, ((v0 + 1) << 6) + swz16(v0 + 1, lane), h1);
        sth(xPh, ((v0 + 2) << 6) + swz16(v0 + 2, lane), h2);
        sth(xPh, ((v0 + 3) << 6) + swz16(v0 + 3, lane), h3);
    }
    __syncthreads();

    // ---- layers 1,2 ----
    for (int l = 0; l < 2; l++) {
        // (a) x-GEMMs (16 waves) + s-GEMM (40 units over 16 waves)
        {
            int mat = wid >> 2, Mt = wid & 3;
            const u16* bp = wlp + l * 20480 + (mat + 1) * 4096;
            int row = Mt * 16 + m;
            f32x4 acc[4];
#pragma unroll
            for (int nt = 0; nt < 4; nt++) acc[nt] = (f32x4){0.f, 0.f, 0.f, 0.f};
#pragma unroll
            for (int kb = 0; kb < 2; kb++) {
                f16x8 a = ldfragh(xPh, (row << 6) + swz16(row, kb * 32 + quad * 8));
#pragma unroll
                for (int nt = 0; nt < 4; nt++) {
                    f16x8 bfr = ldfragh(bp, (((nt << 1) + kb) << 9) + (lane << 3));
                    acc[nt] = __builtin_amdgcn_mfma_f32_16x16x32_f16(a, bfr, acc[nt], 0, 0, 0);
                }
            }
#pragma unroll
            for (int nt = 0; nt < 4; nt++)
#pragma unroll
                for (int r = 0; r < 4; r++) {
                    int orow = Mt * 16 + quad * 4 + r;
                    tLs[mat * 4096 + (orow << 6) + swzp(orow, nt * 16 + m)] = acc[nt][r];
                }

            const u16* sbp = wlp + l * 20480;   // Ws
            for (int u = wid; u < 40; u += 16) {
                int rt = u >> 2, ntq = u & 3;
                int srow = rt * 16 + m;
                int ar = (srow > NEDGE - 1) ? (NEDGE - 1) : srow;
                f32x4 sacc = (f32x4){0.f, 0.f, 0.f, 0.f};
#pragma unroll
                for (int kb = 0; kb < 2; kb++) {
                    f16x8 a = ldfragh(sPh, (ar << 6) + swz16(ar, kb * 32 + quad * 8));
                    f16x8 bfr = ldfragh(sbp, (((ntq << 1) + kb) << 9) + (lane << 3));
                    sacc = __builtin_amdgcn_mfma_f32_16x16x32_f16(a, bfr, sacc, 0, 0, 0);
                }
#pragma unroll
                for (int r = 0; r < 4; r++) {
                    int orow = rt * 16 + quad * 4 + r;
                    if (orow < NEDGE)
                        preL[(orow << 6) + swzp(orow, ntq * 16 + m)] = sacc[r];
                }
            }
        }
        __syncthreads();

        // (b1) edge-parallel update, 4 edges/iter
        for (int base = 0; base < NEDGE; base += 64) {
            int e0 = base + wid;
            int e1i = e0 + 16, e2i = e0 + 32, e3i = e0 + 48;
            int ok1 = e1i < NEDGE, ok2 = e2i < NEDGE, ok3 = e3i < NEDGE;
            int f1 = ok1 ? e1i : e0, f2 = ok2 ? e2i : e0, f3 = ok3 ? e3i : e0;
            int cp0 = rfl(colL[e0]), cp1 = rfl(colL[f1]);
            int cp2 = rfl(colL[f2]), cp3 = rfl(colL[f3]);
            int w0 = cp0 & 255, v0 = (cp0 >> 16) & 255;
            int w1 = cp1 & 255, v1 = (cp1 >> 16) & 255;
            int w2 = cp2 & 255, v2 = (cp2 >> 16) & 255;
            int w3 = cp3 & 255, v3 = (cp3 >> 16) & 255;
            int h0i = (e0 << 6) + swz16(e0, lane);
            int h1i = (f1 << 6) + swz16(f1, lane);
            int h2i = (f2 << 6) + swz16(f2, lane);
            int h3i = (f3 << 6) + swz16(f3, lane);
            int p0i = (e0 << 6) + swzp(e0, lane);
            int p1i = (f1 << 6) + swzp(f1, lane);
            int p2i = (f2 << 6) + swzp(f2, lane);
            int p3i = (f3 << 6) + swzp(f3, lane);
            float ee0 = preL[p0i]
                      + tLs[XI * 4096 + (v0 << 6) + swzp(v0, lane)]
                      + tLs[XJ * 4096 + (w0 << 6) + swzp(w0, lane)];
            float ee1 = preL[p1i]
                      + tLs[XI * 4096 + (v1 << 6) + swzp(v1, lane)]
                      + tLs[XJ * 4096 + (w1 << 6) + swzp(w1, lane)];
            float ee2 = preL[p2i]
                      + tLs[XI * 4096 + (v2 << 6) + swzp(v2, lane)]
                      + tLs[XJ * 4096 + (w2 << 6) + swzp(w2, lane)];
            float ee3 = preL[p3i]
                      + tLs[XI * 4096 + (v3 << 6) + swzp(v3, lane)]
                      + tLs[XJ * 4096 + (w3 << 6) + swzp(w3, lane)];
            float h0, h1, h2, h3;
            ln4_dpp(ee0, ee1, ee2, ee3, h0, h1, h2, h3);
            float s0 = ldh(sPh, h0i) + h0;
            sth(sPh, h0i, s0);
            preL[p0i] = tLs[XV * 4096 + (w0 << 6) + swzp(w0, lane)] * sigm(s0);
            if (ok1) {
                float s1v = ldh(sPh, h1i) + h1;
                sth(sPh, h1i, s1v);
                preL[p1i] = tLs[XV * 4096 + (w1 << 6) + swzp(w1, lane)] * sigm(s1v);
            }
            if (ok2) {
                float s2v = ldh(sPh, h2i) + h2;
                sth(sPh, h2i, s2v);
                preL[p2i] = tLs[XV * 4096 + (w2 << 6) + swzp(w2, lane)] * sigm(s2v);
            }
            if (ok3) {
                float s3v = ldh(sPh, h3i) + h3;
                sth(sPh, h3i, s3v);
                preL[p3i] = tLs[XV * 4096 + (w3 << 6) + swzp(w3, lane)] * sigm(s3v);
            }
        }
        __syncthreads();

        // (b2) per-v aggregation + node update (+ xg partial on last layer)
        {
            int v0 = wid << 2;
            int r0 = rfl(rpL[v0]), r1 = rfl(rpL[v0 + 1]), r2 = rfl(rpL[v0 + 2]);
            int r3 = rfl(rpL[v0 + 3]), r4 = rfl(rpL[v0 + 4]);
            float mc0 = 0.f, mc1 = 0.f, mc2 = 0.f, mc3 = 0.f;
            for (int e = r0; e < r1; e++) mc0 += preL[(e << 6) + swzp(e, lane)];
            for (int e = r1; e < r2; e++) mc1 += preL[(e << 6) + swzp(e, lane)];
            for (int e = r2; e < r3; e++) mc2 += preL[(e << 6) + swzp(e, lane)];
            for (int e = r3; e < r4; e++) mc3 += preL[(e << 6) + swzp(e, lane)];
            float z0 = tLs[XU * 4096 + ((v0 + 0) << 6) + swzp(v0 + 0, lane)] + mc0 * dinvL[v0 + 0];
            float z1 = tLs[XU * 4096 + ((v0 + 1) << 6) + swzp(v0 + 1, lane)] + mc1 * dinvL[v0 + 1];
            float z2 = tLs[XU * 4096 + ((v0 + 2) << 6) + swzp(v0 + 2, lane)] + mc2 * dinvL[v0 + 2];
            float z3 = tLs[XU * 4096 + ((v0 + 3) << 6) + swzp(v0 + 3, lane)] + mc3 * dinvL[v0 + 3];
            float h0, h1, h2, h3;
            ln4_dpp(z0, z1, z2, z3, h0, h1, h2, h3);
            int i0 = ((v0 + 0) << 6) + swz16(v0 + 0, lane);
            int i1 = ((v0 + 1) << 6) + swz16(v0 + 1, lane);
            int i2 = ((v0 + 2) << 6) + swz16(v0 + 2, lane);
            int i3 = ((v0 + 3) << 6) + swz16(v0 + 3, lane);
            float x0 = ldh(xPh, i0) + h0;
            float x1 = ldh(xPh, i1) + h1;
            float x2 = ldh(xPh, i2) + h2;
            float x3 = ldh(xPh, i3) + h3;
            sth(xPh, i0, x0);
            sth(xPh, i1, x1);
            sth(xPh, i2, x2);
            sth(xPh, i3, x3);
            if (l == 1) tLs[(wid << 6) + lane] = x0 + x1 + x2 + x3;   // xg partial
        }
        __syncthreads();
    }

    // ---- xg final ----
    if (t < 64) {
        float s = 0.f;
#pragma unroll
        for (int i = 0; i < 16; i++) s += tLs[(i << 6) + t];
        sth(xg16, t, s);
    }
    __syncthreads();

    // ======== heads (f16 hidden overlays in tLs) ========
    u16* hcP = (u16*)tLs;           // 64 x 192 f16
    u16* hsP = (u16*)tLs + 12288;   // 16 x 256 f16

    // ---- H2: cmlp GEMM1 (waves 0-11) ∥ smlp GEMM1 (waves 12-15) ----
    if (wid < 12) {
        int Mt = wid & 3, ntg = wid >> 2;
        int e = Mt * 16 + m; if (e > 62) e = 62;
        int ai = eALs[e], aj = eALs[EC + e];
        f32x4 acc[4];
#pragma unroll
        for (int j = 0; j < 4; j++) acc[j] = (f32x4){0.f, 0.f, 0.f, 0.f};
#pragma unroll
        for (int kb = 0; kb < 6; kb++) {
            int k = kb * 32 + quad * 8;
            f16x8 a;
            if (k < 64) {
                a = ldfragh(xPh, (ai << 6) + swz16(ai, k));
            } else if (k < 128) {
                a = ldfragh(xPh, (aj << 6) + swz16(aj, k - 64));
            } else {
                a = ldfragh(xg16, k - 128);
            }
#pragma unroll
            for (int j = 0; j < 4; j++) {
                int nt = ntg * 4 + j;
                f16x8 bfr = ldfragh(c1p, ((nt * 6 + kb) << 9) + (lane << 3));
                acc[j] = __builtin_amdgcn_mfma_f32_16x16x32_f16(a, bfr, acc[j], 0, 0, 0);
            }
        }
#pragma unroll
        for (int j = 0; j < 4; j++) {
            int nt = ntg * 4 + j;
#pragma unroll
            for (int r = 0; r < 4; r++) {
                int row = Mt * 16 + quad * 4 + r;
                sth(hcP, row * 192 + swz16(row, nt * 16 + m), fmaxf(acc[j][r], 0.f));
            }
        }
    } else {
        int e2 = (m > 9) ? 9 : m;
        int si = eSLs[e2], sj = eSLs[NSW + e2];
        int sw = swLx[e2];
        f32x4 accS[4];
#pragma unroll
        for (int j = 0; j < 4; j++) accS[j] = (f32x4){0.f, 0.f, 0.f, 0.f};
#pragma unroll
        for (int kb = 0; kb < 8; kb++) {
            int k = kb * 32 + quad * 8;
            f16x8 a;
            if (k < 64) {
                a = ldfragh(sPh, (sw << 6) + swz16(sw, k));
            } else if (k < 128) {
                a = ldfragh(xPh, (si << 6) + swz16(si, k - 64));
            } else if (k < 192) {
                a = ldfragh(xPh, (sj << 6) + swz16(sj, k - 128));
            } else {
                a = ldfragh(xg16, k - 192);
            }
#pragma unroll
            for (int j = 0; j < 4; j++) {
                int nt = (wid - 12) * 4 + j;
                f16x8 bfr = ldfragh(s1p, ((nt * 8 + kb) << 9) + (lane << 3));
                accS[j] = __builtin_amdgcn_mfma_f32_16x16x32_f16(a, bfr, accS[j], 0, 0, 0);
            }
        }
#pragma unroll
        for (int j = 0; j < 4; j++) {
            int nt = (wid - 12) * 4 + j;
#pragma unroll
            for (int r = 0; r < 4; r++) {
                int row = quad * 4 + r;
                sth(hsP, (row << 8) + swz16(row, nt * 16 + m), fmaxf(accS[j][r], 0.f));
            }
        }
    }
    __syncthreads();

    // ---- H3: cmlp GEMM2 (waves 0-3) ∥ smlp GEMM2 (wave 4) ----
    if (wid < 4) {
        f32x4 accD = (f32x4){0.f, 0.f, 0.f, 0.f};
        int row = wid * 16 + m;
#pragma unroll
        for (int kb = 0; kb < 6; kb++) {
            f16x8 a = ldfragh(hcP, row * 192 + swz16(row, kb * 32 + quad * 8));
            f16x8 bfr = ldfragh(c2p, (kb << 9) + (lane << 3));
            accD = __builtin_amdgcn_mfma_f32_16x16x32_f16(a, bfr, accD, 0, 0, 0);
        }
#pragma unroll
        for (int r = 0; r < 4; r++) {
            int row2 = wid * 16 + quad * 4 + r;
            if (row2 < EC && m < 3)
                cmoL[row2 * 3 + m] = 1.f / (1.f + __expf(-accD[r]));
        }
    } else if (wid == 4) {
        f32x4 accT = (f32x4){0.f, 0.f, 0.f, 0.f};
#pragma unroll
        for (int kb = 0; kb < 8; kb++) {
            f16x8 a = ldfragh(hsP, (m << 8) + swz16(m, kb * 32 + quad * 8));
            f16x8 bfr = ldfragh(s2p, (kb << 9) + (lane << 3));
            accT = __builtin_amdgcn_mfma_f32_16x16x32_f16(a, bfr, accT, 0, 0, 0);
        }
#pragma unroll
        for (int r = 0; r < 4; r++) {
            int row = quad * 4 + r;
            if (row < NSW && m < 4)
                smoL[row * 4 + m] = 1.f / (1.f + __expf(-accT[r]));
        }
    }
    __syncthreads();

    // ---- final assembly ----
    if (t < 2 * MNE + VN) {
        float val;
        if (t < MNE) {
            val = (t < EC) ? cmoL[t * 3] - 0.5f : smoL[(t - EC) * 4 + 1] - 0.5f;
        } else if (t < MNE + VN) {
            int i = t - MNE;
            if (i == 0) {
                val = 1.0f;
            } else {
                float acc = 0.f;
                int c = incCnt[i];
                for (int q = 0; q < c; q++) {
                    int em = incM[i * 8 + q];
                    int mm = em >> 1, role = em & 1;
                    float vv = (mm < EC) ? 0.9f + 0.2f * cmoL[mm * 3 + 1 + role]
                                         : 0.9f + 0.2f * smoL[(mm - EC) * 4 + 2 + role];
                    acc += vv;
                }
                val = acc * dinvD[i];
            }
        } else {
            int mm = t - (MNE + VN);
            val = (mm < EC) ? 1.0f : smoL[(mm - EC) * 4];
        }
        size_t oidx = (size_t)b * (2 * MNE + VN) + t;
        if (fl) ((u16*)out_v)[oidx] = f2bf(val);
        else    ((float*)out_v)[oidx] = val;
    }
}

extern "C" void kernel_launch(void* const* d_in, const int* in_sizes, int n_in,
                              void* d_out, int out_size, void* d_ws, size_t ws_size,
                              hipStream_t stream) {
    const int* eA = (const int*)d_in[21];
    const int* eS = (const int*)d_in[22];

    float* pool = (float*)d_ws;
    float* ews     = pool;                       // 128
    float* dinv    = ews + 128;                  // 64
    float* dinvD   = dinv + 64;                  // 64
    int*   row_ptr = (int*)(dinvD + 64);         // 80
    int*   colp    = row_ptr + 80;               // 256
    int*   sw_eidx = colp + 256;                 // 16
    int*   incCnt  = sw_eidx + 16;               // 64
    int*   incM    = incCnt + 64;                // 512
    u16*   c1p = (u16*)(incM + 512);
    u16*   c2p = c1p + 36864;
    u16*   s1p = c2p + 3072;
    u16*   s2p = s1p + 65536;
    u16*   w0p = s2p + 4096;
    u16*   wlp = w0p + 8192;

    CvtArgs ca;
    for (int i = 0; i < 21; i++) ca.src[i] = d_in[i];

    k_prep<<<1 + NPACK, 256, 0, stream>>>(ca, eA, eS,
                                          c1p, c2p, s1p, s2p, w0p, wlp,
                                          ews, dinv, row_ptr, colp, sw_eidx,
                                          dinvD, incCnt, incM);

    k_main<<<BN, 1024, 0, stream>>>(d_in[0], (const u16*)d_in[1], eA, eS,
                                    ews, dinv, row_ptr, colp, sw_eidx,
                                    dinvD, incCnt, incM,
                                    w0p, wlp, c1p, c2p, s1p, s2p,
                                    d_out);
}

// Round 8
// 148.987 us; speedup vs baseline: 1.1415x; 1.0249x over previous
//
#include <hip/hip_runtime.h>

#define BN 200
#define VN 64
#define HIDD 64
#define FINN 32
#define NSW 10
#define EC 63
#define MNE 73
#define NEDGE 146
#define NPACK 256

typedef unsigned short u16;
typedef unsigned int u32;
typedef _Float16 f16;
typedef __attribute__((ext_vector_type(8))) _Float16 f16x8;
typedef __attribute__((ext_vector_type(4))) float f32x4;

__device__ __forceinline__ float bfu(u16 u) { return __uint_as_float(((u32)u) << 16); }
__device__ __forceinline__ u16 f2bf(float f) {
    u32 x = __float_as_uint(f);
    u32 r = x + 0x7fffu + ((x >> 16) & 1u);
    return (u16)(r >> 16);
}
__device__ __forceinline__ float cvtv(const void* p, int i, int fl) {
    return fl ? bfu(((const u16*)p)[i]) : ((const float*)p)[i];
}

// swizzles: u32-granular (f32 planes) and u16-granular (f16 planes); keep 16B groups
__device__ __forceinline__ int swzp(int row, int col) { return col ^ ((row & 7) << 2); }
__device__ __forceinline__ int swz16(int row, int col) { return col ^ ((row & 7) << 3); }

__device__ __forceinline__ float ldh(const u16* P, int i) {
    union { u16 u; f16 h; } c; c.u = P[i];
    return (float)c.h;
}
__device__ __forceinline__ void sth(u16* P, int i, float f) {
    union { u16 u; f16 h; } c; c.h = (f16)f;
    P[i] = c.u;
}
__device__ __forceinline__ u16 f2h(float f) {
    union { u16 u; f16 h; } c; c.h = (f16)f;
    return c.u;
}
__device__ __forceinline__ void unp2(u32 w, float& a, float& b) {
    union { u32 u; f16 h[2]; } c; c.u = w;
    a = (float)c.h[0]; b = (float)c.h[1];
}
__device__ __forceinline__ u32 pk2(float a, float b) {
    union { u32 u; f16 h[2]; } c; c.h[0] = (f16)a; c.h[1] = (f16)b;
    return c.u;
}
__device__ __forceinline__ f16x8 ldfragh(const u16* P, int i0) {
    return *(const f16x8*)&P[i0];
}

// ---- DPP helpers ----
template <int CTRL>
__device__ __forceinline__ float dppadd(float x) {
    int v = __builtin_amdgcn_update_dpp(0, __float_as_int(x), CTRL, 0xf, 0xf, 1);
    return x + __int_as_float(v);
}
template <int N>
__device__ __forceinline__ float rlN(float x) {
    return __int_as_float(__builtin_amdgcn_readlane(__float_as_int(x), N));
}

// dual-half LayerNorm+ReLU on lane-pairs: lanes 0-31 = row A (2 elems/lane),
// lanes 32-63 = row B. 4 DPP row-steps -> row sums at lanes 15/31/47/63.
__device__ __forceinline__ void lnpair(float p0, float p1, int isHi, float& o0, float& o1) {
    float s1 = p0 + p1;
    float s2 = fmaf(p0, p0, p1 * p1);
    s1 = dppadd<0x111>(s1); s1 = dppadd<0x112>(s1); s1 = dppadd<0x114>(s1); s1 = dppadd<0x118>(s1);
    s2 = dppadd<0x111>(s2); s2 = dppadd<0x112>(s2); s2 = dppadd<0x114>(s2); s2 = dppadd<0x118>(s2);
    float a1 = rlN<15>(s1) + rlN<31>(s1);
    float b1 = rlN<47>(s1) + rlN<63>(s1);
    float a2 = rlN<15>(s2) + rlN<31>(s2);
    float b2 = rlN<47>(s2) + rlN<63>(s2);
    float S1 = isHi ? b1 : a1;
    float S2 = isHi ? b2 : a2;
    float mean = S1 * 0.015625f;
    float var = fmaxf(S2 * 0.015625f - mean * mean, 0.f);
    float rn = rsqrtf(var + 1e-5f);
    o0 = fmaxf((p0 - mean) * rn, 0.f);
    o1 = fmaxf((p1 - mean) * rn, 0.f);
}

__device__ __forceinline__ float sigm(float x) {
    return __fdividef(1.f, 1.f + __expf(-x));
}

struct CvtArgs { const void* src[21]; };

// ======== prep: block 0 = topology; blocks 1..NPACK = single-plane f16 weight packing ========
__global__ __launch_bounds__(256) void k_prep(CvtArgs ca, const int* __restrict__ eA,
                                              const int* __restrict__ eS,
                                              u16* __restrict__ c1p, u16* __restrict__ c2p,
                                              u16* __restrict__ s1p, u16* __restrict__ s2p,
                                              u16* __restrict__ w0p, u16* __restrict__ wlp,
                                              float* __restrict__ ews, float* __restrict__ dinv,
                                              int* __restrict__ row_ptr, int* __restrict__ colp,
                                              int* __restrict__ sw_eidx,
                                              float* __restrict__ dinvD, int* __restrict__ incCnt,
                                              int* __restrict__ incM) {
    int t = threadIdx.x;
    int fl = (((const u16*)ca.src[1])[1] == 0x3F80) ? 1 : 0;
    if (blockIdx.x == 0) {
        __shared__ unsigned char flagL[64 * 65];
        __shared__ float wsL[FINN * 64];
        __shared__ float emL[64];
        __shared__ int degL[64], rpS[65], colS[NEDGE + 16];
        __shared__ int eAL[2 * EC], eSL[2 * NSW];

        if (t < 2 * EC) eAL[t] = eA[t];
        if (t >= 128 && t < 128 + 2 * NSW) eSL[t - 128] = eS[t - 128];
        if (t >= 160 && t < 224) emL[t - 160] = cvtv(ca.src[3], t - 160, fl);
        for (int i = t; i < FINN * 64; i += 256) wsL[i] = cvtv(ca.src[4], i, fl);
        for (int i = t; i < 4096; i += 256) {
            float a = cvtv(ca.src[1], i, fl);
            float s = cvtv(ca.src[2], i, fl);
            int r = i >> 6, c = i & 63;
            flagL[r * 65 + c] = (unsigned char)(((a != 0.f || s != 0.f) ? 1 : 0) |
                                                ((s != 0.f) ? 2 : 0));
        }
        __syncthreads();

        if (t < 128) {
            int j = t >> 6, k = t & 63;
            float a = 0.f;
#pragma unroll
            for (int h = 0; h < FINN; h++) a += emL[j * FINN + h] * wsL[h * 64 + k];
            ews[(j << 6) + k] = a;
        }
        if (t < 64) {
            int d = 0;
#pragma unroll
            for (int w = 0; w < 64; w++) d += flagL[t * 65 + w] & 1;
            degL[t] = d;
            dinv[t] = 1.f / fmaxf((float)d, 1.f);
        }
        __syncthreads();
        if (t == 0) {
            int c = 0;
            for (int v = 0; v < 64; v++) { rpS[v] = c; c += degL[v]; }
            rpS[64] = c;
        }
        __syncthreads();
        if (t < 65) row_ptr[t] = rpS[t];
        if (t < 64) {
            int pos = rpS[t];
#pragma unroll
            for (int w = 0; w < 64; w++) {
                int f = flagL[t * 65 + w];
                if (f & 1) colS[pos++] = w | ((f & 2) ? 256 : 0) | (t << 16);
            }
        }
        __syncthreads();
        int tot = rpS[64];
        if (t < tot) colp[t] = colS[t];
        if (t < NSW) {
            int si = eSL[t], sj = eSL[NSW + t];
            int idx = 0;
            for (int e = rpS[si]; e < rpS[si + 1]; e++)
                if ((colS[e] & 255) == sj) idx = e;
            sw_eidx[t] = idx;
        }
        if (t < 64) {
            dinvD[t] = cvtv(ca.src[18], t * 64 + t, fl);
            int cnt = 0;
            for (int m = 0; m < MNE; m++) {
                int par = (m < EC) ? eAL[m] : eSL[m - EC];
                int chi = (m < EC) ? eAL[EC + m] : eSL[NSW + (m - EC)];
                if (par == t && cnt < 8) incM[t * 8 + cnt++] = (m << 1);
                if (chi == t && cnt < 8) incM[t * 8 + cnt++] = (m << 1) | 1;
            }
            incCnt[t] = cnt;
        }
    } else {
        const int T1 = 36864, T2 = T1 + 3072, T3 = T2 + 65536, T4 = T3 + 4096;
        const int T5 = T4 + 8192, TOT = T5 + 40960;
        for (int i = (blockIdx.x - 1) * 256 + t; i < TOT; i += NPACK * 256) {
            int idx = i;
            const void* src;
            u16* dp;
            int K2, N2, nt, rem, loff = 0;
            if (idx < T1) {
                nt = idx / 3072; rem = idx - nt * 3072; src = ca.src[16];
                dp = c1p + idx; K2 = 192; N2 = 192;
            } else if (idx < T2) {
                idx -= T1; nt = 0; rem = idx; src = ca.src[17];
                dp = c2p + idx; K2 = 192; N2 = 3;
            } else if (idx < T3) {
                idx -= T2; nt = idx >> 12; rem = idx & 4095; src = ca.src[14];
                dp = s1p + idx; K2 = 256; N2 = 256;
            } else if (idx < T4) {
                idx -= T3; nt = 0; rem = idx; src = ca.src[15];
                dp = s2p + idx; K2 = 256; N2 = 4;
            } else if (idx < T5) {
                int j = idx - T4;
                int mt = j >> 11;             // 0=Wi 1=Wj 2=U 3=V  (src 5..8)
                int m2 = j & 2047;
                nt = m2 >> 9; rem = m2 & 511; src = ca.src[5 + mt];
                dp = w0p + j; K2 = 32; N2 = 64;
            } else {
                int j = idx - T5;
                int l = j / 20480;
                int jj = j - l * 20480;
                int mt = jj >> 12;            // 0=Ws 1=Wi 2=Wj 3=U 4=V (src 9..13)
                int m2 = jj & 4095;
                nt = m2 >> 10; rem = m2 & 1023; src = ca.src[9 + mt];
                loff = l * 4096;
                dp = wlp + j; K2 = 64; N2 = 64;
            }
            int kb = rem >> 9, r8 = rem & 511, ln = r8 >> 3, jq = r8 & 7;
            int k = kb * 32 + ((ln >> 4) << 3) + jq;
            int n = nt * 16 + (ln & 15);
            float val = 0.f;
            if (n < N2 && k < K2) val = cvtv(src, loff + k * N2 + n, fl);
            *dp = f2h(val);
        }
    }
}

#define XI 0
#define XJ 1
#define XU 2
#define XV 3

// ======== fused whole-model kernel (f16 datapath, paired-lane LN phases) ========
__global__ __launch_bounds__(1024) void k_main(
    const void* __restrict__ xraw, const u16* __restrict__ A_u16,
    const int* __restrict__ eA, const int* __restrict__ eS,
    const float* __restrict__ ews, const float* __restrict__ dinv,
    const int* __restrict__ row_ptr, const int* __restrict__ colp,
    const int* __restrict__ sw_eidx,
    const float* __restrict__ dinvD, const int* __restrict__ incCnt, const int* __restrict__ incM,
    const u16* __restrict__ w0p, const u16* __restrict__ wlp,
    const u16* __restrict__ c1p, const u16* __restrict__ c2p,
    const u16* __restrict__ s1p, const u16* __restrict__ s2p,
    void* __restrict__ out_v)
{
    __shared__ __align__(16) u16 xPh[64 * 64];         // node features, f16
    __shared__ __align__(16) u16 sPh[NEDGE * 64];      // edge states, f16
    __shared__ __align__(16) float preL[NEDGE * 64];   // s@Ws pre-act / gate*xv (f32)
    __shared__ __align__(16) float tLs[4 * 64 * 64];   // xi/xj/xu/xv f32; heads overlay
    __shared__ __align__(16) u16 xg16[64];
    __shared__ float ewsL[128];
    __shared__ float dinvL[64];
    __shared__ int rpL[65];
    __shared__ int colL[NEDGE + 6];
    __shared__ int swLx[NSW];
    __shared__ int eALs[2 * EC], eSLs[2 * NSW];
    __shared__ float cmoL[EC * 3], smoL[NSW * 4];

    int b = blockIdx.x, t = threadIdx.x;
    int lane = t & 63, wid = t >> 6;          // 16 waves
    int m = lane & 15, quad = lane >> 4;
    int half = lane >> 5, hl = lane & 31, c2 = hl << 1;
    int fl = (A_u16[1] == 0x3F80) ? 1 : 0;

    // ---- stage (2 elems/thread, vectorized) ----
    {
        int i2 = t << 1;
        int r = i2 >> 5, c = i2 & 31;
        float va, vb;
        if (fl) {
            u32 wv = ((const u32*)xraw)[(size_t)b * 1024 + t];
            va = bfu((u16)(wv & 0xffffu));
            vb = bfu((u16)(wv >> 16));
        } else {
            float2 f = ((const float2*)xraw)[(size_t)b * 1024 + t];
            va = f.x; vb = f.y;
        }
        *(u32*)&xPh[(r << 6) + swz16(r, c)] = pk2(va, vb);
    }
    if (t < 128) ewsL[t] = ews[t];
    if (t < 64) dinvL[t] = dinv[t];
    if (t < 65) rpL[t] = row_ptr[t];
    if (t < NEDGE) colL[t] = colp[t];
    if (t < NSW) swLx[t] = sw_eidx[t];
    if (t >= 256 && t < 256 + 2 * EC) eALs[t - 256] = eA[t - 256];
    if (t >= 512 && t < 512 + 2 * NSW) eSLs[t - 512] = eS[t - 512];
    __syncthreads();

    // ---- layer 0 transforms: x(64x32) @ {Wi,Wj,U,V}(32x64) ----
    {
        int mat = wid >> 2, Mt = wid & 3;
        const u16* bp = w0p + mat * 2048;
        int row = Mt * 16 + m;
        f16x8 a = ldfragh(xPh, (row << 6) + swz16(row, quad * 8));
        f32x4 acc[4];
#pragma unroll
        for (int nt = 0; nt < 4; nt++) {
            f16x8 bfr = ldfragh(bp, (nt << 9) + (lane << 3));
            acc[nt] = __builtin_amdgcn_mfma_f32_16x16x32_f16(a, bfr, (f32x4){0.f, 0.f, 0.f, 0.f}, 0, 0, 0);
        }
#pragma unroll
        for (int nt = 0; nt < 4; nt++)
#pragma unroll
            for (int r = 0; r < 4; r++) {
                int orow = Mt * 16 + quad * 4 + r;
                tLs[mat * 4096 + (orow << 6) + swzp(orow, nt * 16 + m)] = acc[nt][r];
            }
    }
    __syncthreads();

    // ---- layer 0 B1: paired-lane edge update (8 edges/wave/iter) ----
    for (int base = 0; base < NEDGE; base += 128) {
#pragma unroll
        for (int s = 0; s < 4; s++) {
            int q = (s << 1) + half;
            int e = base + wid + (q << 4);
            int ok = e < NEDGE;
            int ec = ok ? e : (NEDGE - 1);
            int cp = colL[ec];
            int w = cp & 255, v = (cp >> 16) & 255;
            float2 ew = *(const float2*)&ewsL[((((cp >> 8) & 1)) << 6) + c2];
            float2 xi = *(const float2*)&tLs[XI * 4096 + (v << 6) + swzp(v, c2)];
            float2 xj = *(const float2*)&tLs[XJ * 4096 + (w << 6) + swzp(w, c2)];
            float p0 = ew.x + xi.x + xj.x;
            float p1 = ew.y + xi.y + xj.y;
            float h0, h1;
            lnpair(p0, p1, half, h0, h1);
            float2 xv = *(const float2*)&tLs[XV * 4096 + (w << 6) + swzp(w, c2)];
            float2 g;
            g.x = xv.x * sigm(h0);
            g.y = xv.y * sigm(h1);
            if (ok) {
                *(u32*)&sPh[(ec << 6) + swz16(ec, c2)] = pk2(h0, h1);
                *(float2*)&preL[(ec << 6) + swzp(ec, c2)] = g;
            }
        }
    }
    __syncthreads();

    // ---- layer 0 B2: paired-lane per-v aggregation (4 nodes/wave) ----
    {
#pragma unroll
        for (int s = 0; s < 2; s++) {
            int v = (wid << 2) + (s << 1) + half;
            int r0 = rpL[v], r1 = rpL[v + 1];
            float m0 = 0.f, m1 = 0.f;
            for (int e = r0; e < r1; e++) {
                float2 p = *(const float2*)&preL[(e << 6) + swzp(e, c2)];
                m0 += p.x; m1 += p.y;
            }
            float2 xu = *(const float2*)&tLs[XU * 4096 + (v << 6) + swzp(v, c2)];
            float di = dinvL[v];
            float z0 = xu.x + m0 * di, z1 = xu.y + m1 * di;
            float h0, h1;
            lnpair(z0, z1, half, h0, h1);
            *(u32*)&xPh[(v << 6) + swz16(v, c2)] = pk2(h0, h1);
        }
    }
    __syncthreads();

    // ---- layers 1,2 ----
    for (int l = 0; l < 2; l++) {
        // (a) x-GEMMs (16 waves) + s-GEMM (40 units over 16 waves)
        {
            int mat = wid >> 2, Mt = wid & 3;
            const u16* bp = wlp + l * 20480 + (mat + 1) * 4096;
            int row = Mt * 16 + m;
            f32x4 acc[4];
#pragma unroll
            for (int nt = 0; nt < 4; nt++) acc[nt] = (f32x4){0.f, 0.f, 0.f, 0.f};
#pragma unroll
            for (int kb = 0; kb < 2; kb++) {
                f16x8 a = ldfragh(xPh, (row << 6) + swz16(row, kb * 32 + quad * 8));
#pragma unroll
                for (int nt = 0; nt < 4; nt++) {
                    f16x8 bfr = ldfragh(bp, (((nt << 1) + kb) << 9) + (lane << 3));
                    acc[nt] = __builtin_amdgcn_mfma_f32_16x16x32_f16(a, bfr, acc[nt], 0, 0, 0);
                }
            }
#pragma unroll
            for (int nt = 0; nt < 4; nt++)
#pragma unroll
                for (int r = 0; r < 4; r++) {
                    int orow = Mt * 16 + quad * 4 + r;
                    tLs[mat * 4096 + (orow << 6) + swzp(orow, nt * 16 + m)] = acc[nt][r];
                }

            const u16* sbp = wlp + l * 20480;   // Ws
            for (int u = wid; u < 40; u += 16) {
                int rt = u >> 2, ntq = u & 3;
                int srow = rt * 16 + m;
                int ar = (srow > NEDGE - 1) ? (NEDGE - 1) : srow;
                f32x4 sacc = (f32x4){0.f, 0.f, 0.f, 0.f};
#pragma unroll
                for (int kb = 0; kb < 2; kb++) {
                    f16x8 a = ldfragh(sPh, (ar << 6) + swz16(ar, kb * 32 + quad * 8));
                    f16x8 bfr = ldfragh(sbp, (((ntq << 1) + kb) << 9) + (lane << 3));
                    sacc = __builtin_amdgcn_mfma_f32_16x16x32_f16(a, bfr, sacc, 0, 0, 0);
                }
#pragma unroll
                for (int r = 0; r < 4; r++) {
                    int orow = rt * 16 + quad * 4 + r;
                    if (orow < NEDGE)
                        preL[(orow << 6) + swzp(orow, ntq * 16 + m)] = sacc[r];
                }
            }
        }
        __syncthreads();

        // (b1) paired-lane edge update
        for (int base = 0; base < NEDGE; base += 128) {
#pragma unroll
            for (int s = 0; s < 4; s++) {
                int q = (s << 1) + half;
                int e = base + wid + (q << 4);
                int ok = e < NEDGE;
                int ec = ok ? e : (NEDGE - 1);
                int cp = colL[ec];
                int w = cp & 255, v = (cp >> 16) & 255;
                int pidx = (ec << 6) + swzp(ec, c2);
                float2 pre = *(const float2*)&preL[pidx];
                float2 xi = *(const float2*)&tLs[XI * 4096 + (v << 6) + swzp(v, c2)];
                float2 xj = *(const float2*)&tLs[XJ * 4096 + (w << 6) + swzp(w, c2)];
                float p0 = pre.x + xi.x + xj.x;
                float p1 = pre.y + xi.y + xj.y;
                float h0, h1;
                lnpair(p0, p1, half, h0, h1);
                int hidx = (ec << 6) + swz16(ec, c2);
                float so0, so1;
                unp2(*(const u32*)&sPh[hidx], so0, so1);
                float n0 = so0 + h0, n1 = so1 + h1;
                float2 xv = *(const float2*)&tLs[XV * 4096 + (w << 6) + swzp(w, c2)];
                float2 g;
                g.x = xv.x * sigm(n0);
                g.y = xv.y * sigm(n1);
                if (ok) {
                    *(u32*)&sPh[hidx] = pk2(n0, n1);
                    *(float2*)&preL[pidx] = g;
                }
            }
        }
        __syncthreads();

        // (b2) paired-lane per-v aggregation + node update (+ xg partial on last layer)
        {
            float xa0 = 0.f, xa1 = 0.f;
#pragma unroll
            for (int s = 0; s < 2; s++) {
                int v = (wid << 2) + (s << 1) + half;
                int r0 = rpL[v], r1 = rpL[v + 1];
                float m0 = 0.f, m1 = 0.f;
                for (int e = r0; e < r1; e++) {
                    float2 p = *(const float2*)&preL[(e << 6) + swzp(e, c2)];
                    m0 += p.x; m1 += p.y;
                }
                float2 xu = *(const float2*)&tLs[XU * 4096 + (v << 6) + swzp(v, c2)];
                float di = dinvL[v];
                float z0 = xu.x + m0 * di, z1 = xu.y + m1 * di;
                float h0, h1;
                lnpair(z0, z1, half, h0, h1);
                int xi16 = (v << 6) + swz16(v, c2);
                float o0, o1;
                unp2(*(const u32*)&xPh[xi16], o0, o1);
                float x0 = o0 + h0, x1 = o1 + h1;
                *(u32*)&xPh[xi16] = pk2(x0, x1);
                xa0 += x0; xa1 += x1;
            }
            if (l == 1) {
                // scratch layout: tLs[wid*128 + half*64 + h] = partial sum over this
                // wave-half's 2 nodes at feature h (XI quadrant rows 0-31, dead here)
                *(float2*)&tLs[(wid << 7) + (half << 6) + c2] = make_float2(xa0, xa1);
            }
        }
        __syncthreads();
    }

    // ---- xg final ----
    if (t < 64) {
        float s = 0.f;
#pragma unroll
        for (int i = 0; i < 16; i++)
            s += tLs[(i << 7) + t] + tLs[(i << 7) + 64 + t];
        sth(xg16, t, s);
    }
    __syncthreads();

    // ======== heads (f16 hidden overlays in tLs) ========
    u16* hcP = (u16*)tLs;           // 64 x 192 f16
    u16* hsP = (u16*)tLs + 12288;   // 16 x 256 f16

    // ---- H2: cmlp GEMM1 (waves 0-11) ∥ smlp GEMM1 (waves 12-15) ----
    if (wid < 12) {
        int Mt = wid & 3, ntg = wid >> 2;
        int e = Mt * 16 + m; if (e > 62) e = 62;
        int ai = eALs[e], aj = eALs[EC + e];
        f32x4 acc[4];
#pragma unroll
        for (int j = 0; j < 4; j++) acc[j] = (f32x4){0.f, 0.f, 0.f, 0.f};
#pragma unroll
        for (int kb = 0; kb < 6; kb++) {
            int k = kb * 32 + quad * 8;
            f16x8 a;
            if (k < 64) {
                a = ldfragh(xPh, (ai << 6) + swz16(ai, k));
            } else if (k < 128) {
                a = ldfragh(xPh, (aj << 6) + swz16(aj, k - 64));
            } else {
                a = ldfragh(xg16, k - 128);
            }
#pragma unroll
            for (int j = 0; j < 4; j++) {
                int nt = ntg * 4 + j;
                f16x8 bfr = ldfragh(c1p, ((nt * 6 + kb) << 9) + (lane << 3));
                acc[j] = __builtin_amdgcn_mfma_f32_16x16x32_f16(a, bfr, acc[j], 0, 0, 0);
            }
        }
#pragma unroll
        for (int j = 0; j < 4; j++) {
            int nt = ntg * 4 + j;
#pragma unroll
            for (int r = 0; r < 4; r++) {
                int row = Mt * 16 + quad * 4 + r;
                sth(hcP, row * 192 + swz16(row, nt * 16 + m), fmaxf(acc[j][r], 0.f));
            }
        }
    } else {
        int e2 = (m > 9) ? 9 : m;
        int si = eSLs[e2], sj = eSLs[NSW + e2];
        int sw = swLx[e2];
        f32x4 accS[4];
#pragma unroll
        for (int j = 0; j < 4; j++) accS[j] = (f32x4){0.f, 0.f, 0.f, 0.f};
#pragma unroll
        for (int kb = 0; kb < 8; kb++) {
            int k = kb * 32 + quad * 8;
            f16x8 a;
            if (k < 64) {
                a = ldfragh(sPh, (sw << 6) + swz16(sw, k));
            } else if (k < 128) {
                a = ldfragh(xPh, (si << 6) + swz16(si, k - 64));
            } else if (k < 192) {
                a = ldfragh(xPh, (sj << 6) + swz16(sj, k - 128));
            } else {
                a = ldfragh(xg16, k - 192);
            }
#pragma unroll
            for (int j = 0; j < 4; j++) {
                int nt = (wid - 12) * 4 + j;
                f16x8 bfr = ldfragh(s1p, ((nt * 8 + kb) << 9) + (lane << 3));
                accS[j] = __builtin_amdgcn_mfma_f32_16x16x32_f16(a, bfr, accS[j], 0, 0, 0);
            }
        }
#pragma unroll
        for (int j = 0; j < 4; j++) {
            int nt = (wid - 12) * 4 + j;
#pragma unroll
            for (int r = 0; r < 4; r++) {
                int row = quad * 4 + r;
                sth(hsP, (row << 8) + swz16(row, nt * 16 + m), fmaxf(accS[j][r], 0.f));
            }
        }
    }
    __syncthreads();

    // ---- H3: cmlp GEMM2 (waves 0-3) ∥ smlp GEMM2 (wave 4) ----
    if (wid < 4) {
        f32x4 accD = (f32x4){0.f, 0.f, 0.f, 0.f};
        int row = wid * 16 + m;
#pragma unroll
        for (int kb = 0; kb < 6; kb++) {
            f16x8 a = ldfragh(hcP, row * 192 + swz16(row, kb * 32 + quad * 8));
            f16x8 bfr = ldfragh(c2p, (kb << 9) + (lane << 3));
            accD = __builtin_amdgcn_mfma_f32_16x16x32_f16(a, bfr, accD, 0, 0, 0);
        }
#pragma unroll
        for (int r = 0; r < 4; r++) {
            int row2 = wid * 16 + quad * 4 + r;
            if (row2 < EC && m < 3)
                cmoL[row2 * 3 + m] = 1.f / (1.f + __expf(-accD[r]));
        }
    } else if (wid == 4) {
        f32x4 accT = (f32x4){0.f, 0.f, 0.f, 0.f};
#pragma unroll
        for (int kb = 0; kb < 8; kb++) {
            f16x8 a = ldfragh(hsP, (m << 8) + swz16(m, kb * 32 + quad * 8));
            f16x8 bfr = ldfragh(s2p, (kb << 9) + (lane << 3));
            accT = __builtin_amdgcn_mfma_f32_16x16x32_f16(a, bfr, accT, 0, 0, 0);
        }
#pragma unroll
        for (int r = 0; r < 4; r++) {
            int row = quad * 4 + r;
            if (row < NSW && m < 4)
                smoL[row * 4 + m] = 1.f / (1.f + __expf(-accT[r]));
        }
    }
    __syncthreads();

    // ---- final assembly ----
    if (t < 2 * MNE + VN) {
        float val;
        if (t < MNE) {
            val = (t < EC) ? cmoL[t * 3] - 0.5f : smoL[(t - EC) * 4 + 1] - 0.5f;
        } else if (t < MNE + VN) {
            int i = t - MNE;
            if (i == 0) {
                val = 1.0f;
            } else {
                float acc = 0.f;
                int c = incCnt[i];
                for (int q = 0; q < c; q++) {
                    int em = incM[i * 8 + q];
                    int mm = em >> 1, role = em & 1;
                    float vv = (mm < EC) ? 0.9f + 0.2f * cmoL[mm * 3 + 1 + role]
                                         : 0.9f + 0.2f * smoL[(mm - EC) * 4 + 2 + role];
                    acc += vv;
                }
                val = acc * dinvD[i];
            }
        } else {
            int mm = t - (MNE + VN);
            val = (mm < EC) ? 1.0f : smoL[(mm - EC) * 4];
        }
        size_t oidx = (size_t)b * (2 * MNE + VN) + t;
        if (fl) ((u16*)out_v)[oidx] = f2bf(val);
        else    ((float*)out_v)[oidx] = val;
    }
}

extern "C" void kernel_launch(void* const* d_in, const int* in_sizes, int n_in,
                              void* d_out, int out_size, void* d_ws, size_t ws_size,
                              hipStream_t stream) {
    const int* eA = (const int*)d_in[21];
    const int* eS = (const int*)d_in[22];

    float* pool = (float*)d_ws;
    float* ews     = pool;                       // 128
    float* dinv    = ews + 128;                  // 64
    float* dinvD   = dinv + 64;                  // 64
    int*   row_ptr = (int*)(dinvD + 64);         // 80
    int*   colp    = row_ptr + 80;               // 256
    int*   sw_eidx = colp + 256;                 // 16
    int*   incCnt  = sw_eidx + 16;               // 64
    int*   incM    = incCnt + 64;                // 512
    u16*   c1p = (u16*)(incM + 512);
    u16*   c2p = c1p + 36864;
    u16*   s1p = c2p + 3072;
    u16*   s2p = s1p + 65536;
    u16*   w0p = s2p + 4096;
    u16*   wlp = w0p + 8192;

    CvtArgs ca;
    for (int i = 0; i < 21; i++) ca.src[i] = d_in[i];

    k_prep<<<1 + NPACK, 256, 0, stream>>>(ca, eA, eS,
                                          c1p, c2p, s1p, s2p, w0p, wlp,
                                          ews, dinv, row_ptr, colp, sw_eidx,
                                          dinvD, incCnt, incM);

    k_main<<<BN, 1024, 0, stream>>>(d_in[0], (const u16*)d_in[1], eA, eS,
                                    ews, dinv, row_ptr, colp, sw_eidx,
                                    dinvD, incCnt, incM,
                                    w0p, wlp, c1p, c2p, s1p, s2p,
                                    d_out);
}